// Round 13
// baseline (1898.547 us; speedup 1.0000x reference)
//
#include <hip/hip_runtime.h>
#include <hip/hip_bf16.h>
#include <cstdint>
#include <cstddef>

#define B_ROWS 1024
#define N_CAND 50000
#define CTX    96
#define D_IN   128
#define D_MAIN 256
#define D_BLOCK 512
#define N_OUT  10
#define LN_EPS 1e-5f
#define MAXTIE 4096
#define NTOT   (N_CAND + B_ROWS)

typedef unsigned short u16;
typedef __attribute__((ext_vector_type(8))) short bf16x8;
typedef __attribute__((ext_vector_type(4))) float f32x4;

__device__ __forceinline__ u16 bf16_bits(float f) {
    __hip_bfloat16 h = __float2bfloat16(f);
    return *reinterpret_cast<u16*>(&h);
}
__device__ __forceinline__ float bits_to_f32(u16 b) {
    unsigned u = ((unsigned)b) << 16;
    return __uint_as_float(u);
}
__device__ __forceinline__ void split_f32(float v, u16& h, u16& l) {
    h = bf16_bits(v);
    l = bf16_bits(v - bits_to_f32(h));
}
__device__ __forceinline__ float join_f32(u16 h, u16 l) {
    return bits_to_f32(h) + bits_to_f32(l);
}
__device__ __forceinline__ unsigned f2u_mono(float f) {
    unsigned u = __float_as_uint(f);
    return u ^ ((u & 0x80000000u) ? 0xFFFFFFFFu : 0x80000000u);
}

__device__ __forceinline__ void load_lds_16B(const void* gp, void* lp) {
    __builtin_amdgcn_global_load_lds((const __attribute__((address_space(1))) void*)gp,
                                     (__attribute__((address_space(3))) void*)lp,
                                     16, 0, 0);
}

// ---------------------------------------------------------------------------
// Split-bf16 MFMA GEMM (NT). 128x128 tile, BK=32, 256 threads, 16x16x32 MFMA.
// acc += AhBh (+AlBh if A_LO) (+AhBl if B_LO).
// HAS_RES: += residual, fp32 (Rm) or split (Rh,Rl) per RES_SPLIT.
// KEY16: u16 monotone key of (-2*acc+bias) -> Ch (staged LDS store).
// OUT_SPLIT: (Ch,Cl).  OUT_B16: Ch bf16.  OUT_F32: Cf.
// MXFAST: m-tile on blockIdx.x.
// ---------------------------------------------------------------------------
template<bool RELU, bool HAS_BIAS, bool HAS_RES, bool RES_SPLIT, bool KEY16,
         bool OUT_F32, bool OUT_SPLIT, bool OUT_B16, bool A_LO, bool B_LO, bool MXFAST>
__global__ __launch_bounds__(256)
void gemm_split_nt(const u16* __restrict__ Ah, const u16* __restrict__ Al,
                   const u16* __restrict__ Bh, const u16* __restrict__ Bl,
                   const float* __restrict__ bias,
                   const float* __restrict__ Rm,
                   const u16* __restrict__ Rh, const u16* __restrict__ Rl,
                   float* __restrict__ Cf, u16* __restrict__ Ch, u16* __restrict__ Cl,
                   int M, int N, int K)
{
    constexpr int N_LOAD = (2 + (A_LO ? 1 : 0) + (B_LO ? 1 : 0)) * 4096;
    constexpr bool STAGED = KEY16 || OUT_SPLIT || OUT_B16;
    constexpr int SM_U16 = (STAGED && N_LOAD < 16384) ? 16384 : N_LOAD;
    __shared__ __align__(16) u16 smem[SM_U16];
    u16* Ash = smem;
    u16* Asl = A_LO ? smem + 4096 : smem;
    u16* Bsh = smem + 4096 * (1 + (A_LO ? 1 : 0));
    u16* Bsl = B_LO ? Bsh + 4096 : Bsh;

    const int tid  = threadIdx.x;
    const int wave = tid >> 6, lane = tid & 63;
    const int bm = (MXFAST ? blockIdx.x : blockIdx.y) * 128;
    const int bn = (MXFAST ? blockIdx.y : blockIdx.x) * 128;
    const int wm = (wave >> 1) * 64, wn = (wave & 1) * 64;
    const int l16 = lane & 15, quad = lane >> 4;

    const int srow = lane >> 2;
    const int scol = (lane & 3) * 8;

    f32x4 acc[4][4];
    #pragma unroll
    for (int i = 0; i < 4; ++i)
        #pragma unroll
        for (int j = 0; j < 4; ++j)
            acc[i][j] = (f32x4){0.f, 0.f, 0.f, 0.f};

    for (int k0 = 0; k0 < K; k0 += 32) {
        const int r0 = wave * 16 + srow, r1 = r0 + 64;
        int ga0 = bm + r0; if (ga0 > M - 1) ga0 = M - 1;
        int ga1 = bm + r1; if (ga1 > M - 1) ga1 = M - 1;
        int gb0 = bn + r0; if (gb0 > N - 1) gb0 = N - 1;
        int gb1 = bn + r1; if (gb1 > N - 1) gb1 = N - 1;
        const size_t a0 = (size_t)ga0 * K + k0 + scol;
        const size_t a1 = (size_t)ga1 * K + k0 + scol;
        const size_t b0 = (size_t)gb0 * K + k0 + scol;
        const size_t b1 = (size_t)gb1 * K + k0 + scol;

        load_lds_16B(Ah + a0, &Ash[(wave * 16) * 32]);
        load_lds_16B(Ah + a1, &Ash[(64 + wave * 16) * 32]);
        if constexpr (A_LO) {
            load_lds_16B(Al + a0, &Asl[(wave * 16) * 32]);
            load_lds_16B(Al + a1, &Asl[(64 + wave * 16) * 32]);
        }
        load_lds_16B(Bh + b0, &Bsh[(wave * 16) * 32]);
        load_lds_16B(Bh + b1, &Bsh[(64 + wave * 16) * 32]);
        if constexpr (B_LO) {
            load_lds_16B(Bl + b0, &Bsl[(wave * 16) * 32]);
            load_lds_16B(Bl + b1, &Bsl[(64 + wave * 16) * 32]);
        }
        __syncthreads();

        bf16x8 ah[4], al[4], bh[4], bl[4];
        #pragma unroll
        for (int i = 0; i < 4; ++i) {
            ah[i] = *(const bf16x8*)&Ash[(wm + i * 16 + l16) * 32 + quad * 8];
            if constexpr (A_LO)
                al[i] = *(const bf16x8*)&Asl[(wm + i * 16 + l16) * 32 + quad * 8];
        }
        #pragma unroll
        for (int j = 0; j < 4; ++j) {
            bh[j] = *(const bf16x8*)&Bsh[(wn + j * 16 + l16) * 32 + quad * 8];
            if constexpr (B_LO)
                bl[j] = *(const bf16x8*)&Bsl[(wn + j * 16 + l16) * 32 + quad * 8];
        }

        #pragma unroll
        for (int i = 0; i < 4; ++i)
            #pragma unroll
            for (int j = 0; j < 4; ++j) {
                acc[i][j] = __builtin_amdgcn_mfma_f32_16x16x32_bf16(ah[i], bh[j], acc[i][j], 0, 0, 0);
                if constexpr (A_LO)
                    acc[i][j] = __builtin_amdgcn_mfma_f32_16x16x32_bf16(al[i], bh[j], acc[i][j], 0, 0, 0);
                if constexpr (B_LO)
                    acc[i][j] = __builtin_amdgcn_mfma_f32_16x16x32_bf16(ah[i], bl[j], acc[i][j], 0, 0, 0);
            }
        __syncthreads();
    }

    float bvj[4];
    #pragma unroll
    for (int j = 0; j < 4; ++j) {
        const int n = bn + wn + j * 16 + l16;
        bvj[j] = ((HAS_BIAS || KEY16) && n < N) ? bias[n] : 0.f;
    }
    auto compute = [&](int i, int j, int r) -> float {
        float v = acc[i][j][r];
        if (KEY16) return -2.f * v + bvj[j];
        if (HAS_BIAS) v += bvj[j];
        if (RELU)     v = fmaxf(v, 0.f);
        if (HAS_RES) {
            const int n = bn + wn + j * 16 + l16;
            const int m = bm + wm + i * 16 + quad * 4 + r;
            if constexpr (RES_SPLIT)
                v += join_f32(Rh[(size_t)m * N + n], Rl[(size_t)m * N + n]);
            else
                v += Rm[(size_t)m * N + n];
        }
        return v;
    };

    if constexpr (OUT_F32) {
        #pragma unroll
        for (int j = 0; j < 4; ++j) {
            const int n = bn + wn + j * 16 + l16;
            if (n >= N) continue;
            #pragma unroll
            for (int i = 0; i < 4; ++i)
                #pragma unroll
                for (int r = 0; r < 4; ++r) {
                    const int m = bm + wm + i * 16 + quad * 4 + r;
                    if (m >= M) continue;
                    Cf[(size_t)m * N + n] = compute(i, j, r);
                }
        }
    }

    if constexpr (STAGED) {
        u16* Cs = smem;
        const int phases = OUT_SPLIT ? 2 : 1;
        for (int ph = 0; ph < phases; ++ph) {
            __syncthreads();
            #pragma unroll
            for (int j = 0; j < 4; ++j) {
                const int nl = wn + j * 16 + l16;
                if (bn + nl >= N) continue;
                #pragma unroll
                for (int i = 0; i < 4; ++i)
                    #pragma unroll
                    for (int r = 0; r < 4; ++r) {
                        const int ml = wm + i * 16 + quad * 4 + r;
                        if (bm + ml >= M) continue;
                        const float v = compute(i, j, r);
                        u16 out;
                        if (KEY16)        out = (u16)(f2u_mono(v) >> 16);
                        else if (OUT_B16) out = bf16_bits(v);
                        else { u16 h, l; split_f32(v, h, l); out = ph ? l : h; }
                        Cs[ml * 128 + nl] = out;
                    }
            }
            __syncthreads();
            u16* dstB = (OUT_SPLIT && ph) ? Cl : Ch;
            const int row = tid >> 1, seg = (tid & 1) * 64;
            const int m = bm + row;
            if (m < M) {
                const int ncols = N - bn;
                u16* dst = dstB + (size_t)m * N + bn + seg;
                const u16* srcp = &Cs[row * 128 + seg];
                if (ncols >= 128) {
                    #pragma unroll
                    for (int c = 0; c < 8; ++c)
                        *reinterpret_cast<uint4*>(dst + c * 8) =
                            *reinterpret_cast<const uint4*>(srcp + c * 8);
                } else {
                    for (int e = 0; e < 64; ++e)
                        if (seg + e < ncols) dst[e] = srcp[e];
                }
            }
        }
    }
}

// ---------------------------------------------------------------------------
// T-MLP GEMM1 with fused diff gather (R10-proven version: split A, 3 MFMA):
//   A[bc,k] = split(k_x[b] - cand_k[idx[bc]]);  C = bf16(relu(A@B^T + bias))
// ---------------------------------------------------------------------------
__global__ __launch_bounds__(256)
void gemm_tmlp1(const u16* __restrict__ kh, const u16* __restrict__ kl,
                const u16* __restrict__ ckh, const u16* __restrict__ ckl,
                const int* __restrict__ idx, int b_base,
                const u16* __restrict__ Bh, const u16* __restrict__ Bl,
                const float* __restrict__ bias, u16* __restrict__ Ch,
                int M, int N, int K)
{
    __shared__ __align__(16) u16 smem[16384];
    u16* Ash = smem;
    u16* Asl = smem + 4096;
    u16* Bsh = smem + 8192;
    u16* Bsl = smem + 12288;

    const int tid  = threadIdx.x;
    const int wave = tid >> 6, lane = tid & 63;
    const int bm = blockIdx.y * 128, bn = blockIdx.x * 128;
    const int wm = (wave >> 1) * 64, wn = (wave & 1) * 64;
    const int l16 = lane & 15, quad = lane >> 4;
    const int srow = lane >> 2, scol = (lane & 3) * 8;

    const int rowA = tid >> 1;
    const int c0 = (tid & 1) * 16;
    int bcl = bm + rowA; if (bcl > M - 1) bcl = M - 1;
    const int brow = b_base + bcl / CTX;
    const int id = idx[bcl];
    const u16* kph = kh + (size_t)brow * D_MAIN;
    const u16* kpl = kl + (size_t)brow * D_MAIN;
    const u16* cph = ckh + (size_t)id * D_MAIN;
    const u16* cpl = ckl + (size_t)id * D_MAIN;

    f32x4 acc[4][4];
    #pragma unroll
    for (int i = 0; i < 4; ++i)
        #pragma unroll
        for (int j = 0; j < 4; ++j)
            acc[i][j] = (f32x4){0.f, 0.f, 0.f, 0.f};

    for (int k0 = 0; k0 < K; k0 += 32) {
        {
            const int c = k0 + c0;
            __align__(16) u16 th[16], tl[16];
            #pragma unroll
            for (int g = 0; g < 4; ++g) {
                const ushort4 a  = *(const ushort4*)(kph + c + g * 4);
                const ushort4 b_ = *(const ushort4*)(kpl + c + g * 4);
                const ushort4 cc = *(const ushort4*)(cph + c + g * 4);
                const ushort4 dd = *(const ushort4*)(cpl + c + g * 4);
                const float d0 = join_f32(a.x, b_.x) - join_f32(cc.x, dd.x);
                const float d1 = join_f32(a.y, b_.y) - join_f32(cc.y, dd.y);
                const float d2 = join_f32(a.z, b_.z) - join_f32(cc.z, dd.z);
                const float d3 = join_f32(a.w, b_.w) - join_f32(cc.w, dd.w);
                split_f32(d0, th[g*4+0], tl[g*4+0]);
                split_f32(d1, th[g*4+1], tl[g*4+1]);
                split_f32(d2, th[g*4+2], tl[g*4+2]);
                split_f32(d3, th[g*4+3], tl[g*4+3]);
            }
            *(uint4*)&Ash[rowA * 32 + c0]     = *(const uint4*)&th[0];
            *(uint4*)&Ash[rowA * 32 + c0 + 8] = *(const uint4*)&th[8];
            *(uint4*)&Asl[rowA * 32 + c0]     = *(const uint4*)&tl[0];
            *(uint4*)&Asl[rowA * 32 + c0 + 8] = *(const uint4*)&tl[8];
        }
        {
            const int r0 = wave * 16 + srow, r1 = r0 + 64;
            int gb0 = bn + r0; if (gb0 > N - 1) gb0 = N - 1;
            int gb1 = bn + r1; if (gb1 > N - 1) gb1 = N - 1;
            const size_t b0 = (size_t)gb0 * K + k0 + scol;
            const size_t b1 = (size_t)gb1 * K + k0 + scol;
            load_lds_16B(Bh + b0, &Bsh[(wave * 16) * 32]);
            load_lds_16B(Bh + b1, &Bsh[(64 + wave * 16) * 32]);
            load_lds_16B(Bl + b0, &Bsl[(wave * 16) * 32]);
            load_lds_16B(Bl + b1, &Bsl[(64 + wave * 16) * 32]);
        }
        __syncthreads();

        bf16x8 ah[4], al[4], bh[4], bl[4];
        #pragma unroll
        for (int i = 0; i < 4; ++i) {
            ah[i] = *(const bf16x8*)&Ash[(wm + i * 16 + l16) * 32 + quad * 8];
            al[i] = *(const bf16x8*)&Asl[(wm + i * 16 + l16) * 32 + quad * 8];
        }
        #pragma unroll
        for (int j = 0; j < 4; ++j) {
            bh[j] = *(const bf16x8*)&Bsh[(wn + j * 16 + l16) * 32 + quad * 8];
            bl[j] = *(const bf16x8*)&Bsl[(wn + j * 16 + l16) * 32 + quad * 8];
        }

        #pragma unroll
        for (int i = 0; i < 4; ++i)
            #pragma unroll
            for (int j = 0; j < 4; ++j) {
                acc[i][j] = __builtin_amdgcn_mfma_f32_16x16x32_bf16(ah[i], bh[j], acc[i][j], 0, 0, 0);
                acc[i][j] = __builtin_amdgcn_mfma_f32_16x16x32_bf16(al[i], bh[j], acc[i][j], 0, 0, 0);
                acc[i][j] = __builtin_amdgcn_mfma_f32_16x16x32_bf16(ah[i], bl[j], acc[i][j], 0, 0, 0);
            }
        __syncthreads();
    }

    float bvj[4];
    #pragma unroll
    for (int j = 0; j < 4; ++j) {
        const int n = bn + wn + j * 16 + l16;
        bvj[j] = (n < N) ? bias[n] : 0.f;
    }

    u16* Cs = smem;
    __syncthreads();
    #pragma unroll
    for (int j = 0; j < 4; ++j) {
        const int nl = wn + j * 16 + l16;
        if (bn + nl >= N) continue;
        #pragma unroll
        for (int i = 0; i < 4; ++i)
            #pragma unroll
            for (int r = 0; r < 4; ++r) {
                const int ml = wm + i * 16 + quad * 4 + r;
                if (bm + ml >= M) continue;
                const float v = fmaxf(acc[i][j][r] + bvj[j], 0.f);
                Cs[ml * 128 + nl] = bf16_bits(v);
            }
    }
    __syncthreads();
    const int row = tid >> 1, seg = (tid & 1) * 64;
    const int m = bm + row;
    if (m < M) {
        u16* dst = Ch + (size_t)m * N + bn + seg;
        const u16* srcp = &Cs[row * 128 + seg];
        #pragma unroll
        for (int c = 0; c < 8; ++c)
            *reinterpret_cast<uint4*>(dst + c * 8) =
                *reinterpret_cast<const uint4*>(srcp + c * 8);
    }
}

// ---------------------------------------------------------------------------
// fp32 128x128 GEMM (post blocks)
// ---------------------------------------------------------------------------
template<bool RELU, bool HAS_BIAS, bool HAS_RES>
__global__ __launch_bounds__(256)
void gemm128(const float* __restrict__ A, const float* __restrict__ Bm,
             const float* __restrict__ bias, const float* __restrict__ Rm,
             float* __restrict__ C, int M, int N, int K)
{
    __shared__ float As[16][128];
    __shared__ float Bs[16][128];
    const int tid = threadIdx.x;
    const int bm = blockIdx.y * 128;
    const int bn = blockIdx.x * 128;

    const int ar = tid >> 1;
    const int ak = (tid & 1) << 3;
    const int kb = tid >> 4;
    const int nb0 = (tid & 15) << 3;
    const int my = (tid >> 4) << 3;
    const int nx = (tid & 15) << 3;

    float acc[8][8] = {};

    for (int k0 = 0; k0 < K; k0 += 16) {
        {
            float4 v0 = make_float4(0.f,0.f,0.f,0.f), v1 = v0;
            const int gm = bm + ar;
            if (gm < M) {
                const float* ap = A + (size_t)gm * K + k0 + ak;
                v0 = *(const float4*)ap;
                v1 = *(const float4*)(ap + 4);
            }
            As[ak+0][ar]=v0.x; As[ak+1][ar]=v0.y; As[ak+2][ar]=v0.z; As[ak+3][ar]=v0.w;
            As[ak+4][ar]=v1.x; As[ak+5][ar]=v1.y; As[ak+6][ar]=v1.z; As[ak+7][ar]=v1.w;
        }
        {
            const float* bp = Bm + (size_t)(k0 + kb) * N + bn + nb0;
            *(float4*)&Bs[kb][nb0]   = *(const float4*)bp;
            *(float4*)&Bs[kb][nb0+4] = *(const float4*)(bp + 4);
        }
        __syncthreads();

        #pragma unroll
        for (int k = 0; k < 16; ++k) {
            float a[8], b[8];
            *(float4*)&a[0] = *(const float4*)&As[k][my];
            *(float4*)&a[4] = *(const float4*)&As[k][my+4];
            *(float4*)&b[0] = *(const float4*)&Bs[k][nx];
            *(float4*)&b[4] = *(const float4*)&Bs[k][nx+4];
            #pragma unroll
            for (int i = 0; i < 8; ++i)
                #pragma unroll
                for (int j = 0; j < 8; ++j)
                    acc[i][j] = fmaf(a[i], b[j], acc[i][j]);
        }
        __syncthreads();
    }

    #pragma unroll
    for (int i = 0; i < 8; ++i) {
        const int m = bm + my + i;
        if (m >= M) continue;
        #pragma unroll
        for (int j = 0; j < 8; j += 4) {
            const int n = bn + nx + j;
            if (n >= N) continue;
            float4 v = make_float4(acc[i][j], acc[i][j+1], acc[i][j+2], acc[i][j+3]);
            if (HAS_BIAS) {
                const float4 q = *(const float4*)(bias + n);
                v.x += q.x; v.y += q.y; v.z += q.z; v.w += q.w;
            }
            if (RELU) {
                v.x = fmaxf(v.x, 0.f); v.y = fmaxf(v.y, 0.f);
                v.z = fmaxf(v.z, 0.f); v.w = fmaxf(v.w, 0.f);
            }
            if (HAS_RES) {
                const float4 q = *(const float4*)(Rm + (size_t)m * N + n);
                v.x += q.x; v.y += q.y; v.z += q.z; v.w += q.w;
            }
            *(float4*)(C + (size_t)m * N + n) = v;
        }
    }
}

// ---------------------------------------------------------------------------
// Small-N fp32 GEMM (head, N=10)
// ---------------------------------------------------------------------------
__global__ __launch_bounds__(256)
void gemm_head(const float* __restrict__ A, const float* __restrict__ Bm,
               const float* __restrict__ bias, float* __restrict__ C,
               int M, int N, int K)
{
    __shared__ float As[16][64];
    __shared__ float Bs[16][64];
    const int tid = threadIdx.x;
    const int bm = blockIdx.y * 64;

    const int a_m = tid >> 2;
    const int a_k = (tid & 3) << 2;
    const int b_k = tid >> 4;
    const int b_n = (tid & 15) << 2;
    const int my = (tid >> 4) << 2;
    const int nx = (tid & 15) << 2;

    float acc[4][4] = {};

    for (int k0 = 0; k0 < K; k0 += 16) {
        float4 av = make_float4(0.f,0.f,0.f,0.f);
        const int gm = bm + a_m;
        if (gm < M) av = *(const float4*)(A + (size_t)gm * K + k0 + a_k);
        As[a_k+0][a_m]=av.x; As[a_k+1][a_m]=av.y; As[a_k+2][a_m]=av.z; As[a_k+3][a_m]=av.w;

        float4 bv = make_float4(0.f,0.f,0.f,0.f);
        const float* bp = Bm + (size_t)(k0 + b_k) * N + b_n;
        if (b_n + 0 < N) bv.x = bp[0];
        if (b_n + 1 < N) bv.y = bp[1];
        if (b_n + 2 < N) bv.z = bp[2];
        if (b_n + 3 < N) bv.w = bp[3];
        *(float4*)&Bs[b_k][b_n] = bv;

        __syncthreads();
        #pragma unroll
        for (int k = 0; k < 16; ++k) {
            const float4 a4 = *(const float4*)&As[k][my];
            const float4 b4 = *(const float4*)&Bs[k][nx];
            const float a[4] = {a4.x,a4.y,a4.z,a4.w};
            const float b[4] = {b4.x,b4.y,b4.z,b4.w};
            #pragma unroll
            for (int i = 0; i < 4; ++i)
                #pragma unroll
                for (int j = 0; j < 4; ++j)
                    acc[i][j] = fmaf(a[i], b[j], acc[i][j]);
        }
        __syncthreads();
    }

    #pragma unroll
    for (int i = 0; i < 4; ++i) {
        const int m = bm + my + i;
        if (m >= M) continue;
        #pragma unroll
        for (int j = 0; j < 4; ++j) {
            const int n = nx + j;
            if (n >= N) continue;
            C[(size_t)m * N + n] = acc[i][j] + bias[n];
        }
    }
}

// ---------------------------------------------------------------------------
// LayerNorm over 256 cols. IN_SPLIT: input (Xh,Xl) else Xf.
// OUT_SPLIT: output (Yh,Yl) else Yf f32.
// ---------------------------------------------------------------------------
template<bool RELU, bool IN_SPLIT, bool OUT_SPLIT>
__global__ __launch_bounds__(256)
void ln_kernel(const float* __restrict__ Xf,
               const u16* __restrict__ Xh, const u16* __restrict__ Xl,
               const float* __restrict__ g, const float* __restrict__ b,
               float* __restrict__ Yf, u16* __restrict__ Yh, u16* __restrict__ Yl)
{
    const int row = blockIdx.x, tid = threadIdx.x;
    float x;
    if (IN_SPLIT)
        x = join_f32(Xh[(size_t)row * D_MAIN + tid], Xl[(size_t)row * D_MAIN + tid]);
    else
        x = Xf[(size_t)row * D_MAIN + tid];
    __shared__ float red[4];
    const int lane = tid & 63, wid = tid >> 6;

    float s = x;
    #pragma unroll
    for (int off = 32; off; off >>= 1) s += __shfl_down(s, off, 64);
    if (lane == 0) red[wid] = s;
    __syncthreads();
    const float mean = (red[0] + red[1] + red[2] + red[3]) * (1.f / D_MAIN);
    __syncthreads();

    const float xm = x - mean;
    s = xm * xm;
    #pragma unroll
    for (int off = 32; off; off >>= 1) s += __shfl_down(s, off, 64);
    if (lane == 0) red[wid] = s;
    __syncthreads();
    const float var = (red[0] + red[1] + red[2] + red[3]) * (1.f / D_MAIN);

    float y = xm / sqrtf(var + LN_EPS) * g[tid] + b[tid];
    if (RELU) y = fmaxf(y, 0.f);
    if (OUT_SPLIT) {
        u16 h, l; split_f32(y, h, l);
        Yh[(size_t)row * D_MAIN + tid] = h;
        Yl[(size_t)row * D_MAIN + tid] = l;
    } else {
        Yf[(size_t)row * D_MAIN + tid] = y;
    }
}

// ---------------------------------------------------------------------------
// ||cand_k[n]||^2 from split
// ---------------------------------------------------------------------------
__global__ __launch_bounds__(64)
void cn2_kernel(const u16* __restrict__ ckh, const u16* __restrict__ ckl,
                float* __restrict__ out)
{
    const int row = blockIdx.x, lane = threadIdx.x;
    const ushort4 h4 = *(const ushort4*)(ckh + (size_t)row * D_MAIN + lane * 4);
    const ushort4 l4 = *(const ushort4*)(ckl + (size_t)row * D_MAIN + lane * 4);
    const float c0 = join_f32(h4.x, l4.x), c1 = join_f32(h4.y, l4.y);
    const float c2 = join_f32(h4.z, l4.z), c3 = join_f32(h4.w, l4.w);
    float s = c0*c0 + c1*c1 + c2*c2 + c3*c3;
    #pragma unroll
    for (int off = 32; off; off >>= 1) s += __shfl_down(s, off, 64);
    if (lane == 0) out[row] = s;
}

// ---------------------------------------------------------------------------
// conversions
// ---------------------------------------------------------------------------
__global__ __launch_bounds__(256)
void f32_to_split_kernel(const float* __restrict__ src, u16* __restrict__ hi,
                         u16* __restrict__ lo, int n)
{
    int i = blockIdx.x * 256 + threadIdx.x;
    if (i < n) {
        u16 h, l; split_f32(src[i], h, l);
        hi[i] = h; lo[i] = l;
    }
}

struct TrD { const float* s; u16* dh; u16* dl; int R; int C; };
struct TrD8 { TrD d[8]; };

__global__ __launch_bounds__(256)
void transpose_all_kernel(TrD8 descs)
{
    const TrD D = descs.d[blockIdx.y];
    const int n = D.R * D.C;
    int idx = blockIdx.x * 256 + threadIdx.x;
    if (idx < n) {
        const int r = idx / D.C, c = idx % D.C;
        u16 h, l; split_f32(D.s[idx], h, l);
        D.dh[(size_t)c * D.R + r] = h;
        D.dl[(size_t)c * D.R + r] = l;
    }
}

__global__ __launch_bounds__(256)
void join_rows_kernel(const u16* __restrict__ hi, const u16* __restrict__ lo,
                      float* __restrict__ dst, int n)
{
    int i = blockIdx.x * 256 + threadIdx.x;
    if (i < n) dst[i] = join_f32(hi[i], lo[i]);
}

// ---------------------------------------------------------------------------
// Top-96 smallest per row on u16 keys; conflict-free hist[bin][64 replicas].
// ---------------------------------------------------------------------------
__global__ __launch_bounds__(1024)
void topk96_u16_kernel(const u16* __restrict__ keys, int* __restrict__ idx_out,
                       int* __restrict__ tiebuf, int* __restrict__ tiecnt,
                       int* __restrict__ lesscnt)
{
    const int row = blockIdx.x;
    const u16* krow = keys + (size_t)row * N_CAND;
    const int tid = threadIdx.x;
    const int rep = tid & 63;

    __shared__ unsigned hist[256 * 64];
    __shared__ unsigned hsum[256];
    __shared__ unsigned sh_bin, sh_need;
    __shared__ int cntLess, cntEq;

    #pragma unroll
    for (int i = 0; i < 16; ++i) hist[tid + i * 1024] = 0;
    __syncthreads();
    for (int i = tid; i < N_CAND / 8; i += 1024) {
        const uint4 v = ((const uint4*)krow)[i];
        const unsigned w[4] = {v.x, v.y, v.z, v.w};
        #pragma unroll
        for (int e = 0; e < 4; ++e) {
            atomicAdd(&hist[(((w[e] >> 8) & 0xFFu)) * 64 + rep], 1u);
            atomicAdd(&hist[((w[e] >> 24)) * 64 + rep], 1u);
        }
    }
    __syncthreads();
    if (tid < 256) {
        unsigned s = 0;
        #pragma unroll
        for (int r = 0; r < 64; ++r) s += hist[tid * 64 + ((r + tid) & 63)];
        hsum[tid] = s;
    }
    __syncthreads();
    int need = CTX;
    if (tid < 64) {
        const unsigned b0 = hsum[tid*4+0], b1 = hsum[tid*4+1],
                       b2 = hsum[tid*4+2], b3 = hsum[tid*4+3];
        const unsigned lsum = b0 + b1 + b2 + b3;
        unsigned pre = lsum;
        #pragma unroll
        for (int off = 1; off < 64; off <<= 1) {
            const unsigned t = __shfl_up(pre, off, 64);
            if (tid >= off) pre += t;
        }
        const unsigned excl = pre - lsum;
        const unsigned nd = (unsigned)need;
        if (excl < nd && excl + lsum >= nd) {
            unsigned bin, rem;
            if      (excl + b0 >= nd)           { bin = tid*4+0; rem = nd - excl; }
            else if (excl + b0 + b1 >= nd)      { bin = tid*4+1; rem = nd - excl - b0; }
            else if (excl + b0 + b1 + b2 >= nd) { bin = tid*4+2; rem = nd - excl - b0 - b1; }
            else                                { bin = tid*4+3; rem = nd - excl - b0 - b1 - b2; }
            sh_bin = bin; sh_need = rem;
        }
    }
    __syncthreads();
    const unsigned hb = sh_bin;
    need = (int)sh_need;
    __syncthreads();

    #pragma unroll
    for (int i = 0; i < 16; ++i) hist[tid + i * 1024] = 0;
    __syncthreads();
    for (int i = tid; i < N_CAND / 8; i += 1024) {
        const uint4 v = ((const uint4*)krow)[i];
        const unsigned w[4] = {v.x, v.y, v.z, v.w};
        #pragma unroll
        for (int e = 0; e < 4; ++e) {
            const unsigned k0 = w[e] & 0xFFFFu, k1 = w[e] >> 16;
            if ((k0 >> 8) == hb) atomicAdd(&hist[(k0 & 255u) * 64 + rep], 1u);
            if ((k1 >> 8) == hb) atomicAdd(&hist[(k1 & 255u) * 64 + rep], 1u);
        }
    }
    __syncthreads();
    if (tid < 256) {
        unsigned s = 0;
        #pragma unroll
        for (int r = 0; r < 64; ++r) s += hist[tid * 64 + ((r + tid) & 63)];
        hsum[tid] = s;
    }
    __syncthreads();
    if (tid < 64) {
        const unsigned b0 = hsum[tid*4+0], b1 = hsum[tid*4+1],
                       b2 = hsum[tid*4+2], b3 = hsum[tid*4+3];
        const unsigned lsum = b0 + b1 + b2 + b3;
        unsigned pre = lsum;
        #pragma unroll
        for (int off = 1; off < 64; off <<= 1) {
            const unsigned t = __shfl_up(pre, off, 64);
            if (tid >= off) pre += t;
        }
        const unsigned excl = pre - lsum;
        const unsigned nd = (unsigned)need;
        if (excl < nd && excl + lsum >= nd) {
            unsigned bin, rem;
            if      (excl + b0 >= nd)           { bin = tid*4+0; rem = nd - excl; }
            else if (excl + b0 + b1 >= nd)      { bin = tid*4+1; rem = nd - excl - b0; }
            else if (excl + b0 + b1 + b2 >= nd) { bin = tid*4+2; rem = nd - excl - b0 - b1; }
            else                                { bin = tid*4+3; rem = nd - excl - b0 - b1 - b2; }
            sh_bin = bin; sh_need = rem;
        }
    }
    __syncthreads();
    const unsigned T16 = (hb << 8) | sh_bin;
    need = (int)sh_need;

    if (tid == 0) { cntLess = 0; cntEq = 0; }
    __syncthreads();

    for (int i = tid; i < N_CAND / 8; i += 1024) {
        const uint4 v = ((const uint4*)krow)[i];
        const unsigned w[4] = {v.x, v.y, v.z, v.w};
        #pragma unroll
        for (int e = 0; e < 4; ++e) {
            const unsigned k0 = w[e] & 0xFFFFu, k1 = w[e] >> 16;
            const int n0 = i * 8 + e * 2, n1 = n0 + 1;
            if (k0 < T16) {
                const int p = atomicAdd(&cntLess, 1);
                idx_out[row * CTX + p] = n0;
            } else if (k0 == T16) {
                const int p = atomicAdd(&cntEq, 1);
                if (p < MAXTIE) tiebuf[(size_t)row * MAXTIE + p] = n0;
            }
            if (k1 < T16) {
                const int p = atomicAdd(&cntLess, 1);
                idx_out[row * CTX + p] = n1;
            } else if (k1 == T16) {
                const int p = atomicAdd(&cntEq, 1);
                if (p < MAXTIE) tiebuf[(size_t)row * MAXTIE + p] = n1;
            }
        }
    }
    __syncthreads();
    if (tid == 0) {
        lesscnt[row] = cntLess;
        tiecnt[row] = (cntEq < MAXTIE) ? cntEq : MAXTIE;
    }
}

// ---------------------------------------------------------------------------
// Fused: exact fp32 tie-break + exact sval for selected 96 + softmax.
// ---------------------------------------------------------------------------
__global__ __launch_bounds__(256)
void select_kernel(const u16* __restrict__ kh, const u16* __restrict__ kl,
                   const u16* __restrict__ ckh, const u16* __restrict__ ckl,
                   const float* __restrict__ ck2,
                   const int* __restrict__ tiebuf, const int* __restrict__ tiecnt,
                   const int* __restrict__ lesscnt,
                   int* __restrict__ idx_out, float* __restrict__ probs)
{
    const int row = blockIdx.x;
    const int tid = threadIdx.x;
    const int T = tiecnt[row];
    const int less = lesscnt[row];
    const int need = CTX - less;

    __shared__ float kvs[D_MAIN];
    __shared__ int   sel[CTX];
    __shared__ float svals[CTX];
    __shared__ float sv[MAXTIE];
    __shared__ unsigned hist[256];
    __shared__ unsigned sh_bin, sh_need;
    __shared__ int c1, c2;
    __shared__ float red[128];

    if (tid < D_MAIN)
        kvs[tid] = join_f32(kh[(size_t)row * D_MAIN + tid], kl[(size_t)row * D_MAIN + tid]);
    if (tid < CTX && tid < less) sel[tid] = idx_out[row * CTX + tid];
    __syncthreads();

    if (T <= need) {
        for (int t = tid; t < T; t += 256) {
            sel[less + t] = tiebuf[(size_t)row * MAXTIE + t];
            idx_out[row * CTX + less + t] = sel[less + t];
        }
    } else {
        for (int t = tid; t < T; t += 256) {
            const int c = tiebuf[(size_t)row * MAXTIE + t];
            const u16* ch = ckh + (size_t)c * D_MAIN;
            const u16* cl = ckl + (size_t)c * D_MAIN;
            float s = 0.f;
            for (int d = 0; d < D_MAIN; d += 4) {
                const ushort4 h4 = *(const ushort4*)(ch + d);
                const ushort4 l4 = *(const ushort4*)(cl + d);
                s += kvs[d+0] * join_f32(h4.x, l4.x) + kvs[d+1] * join_f32(h4.y, l4.y)
                   + kvs[d+2] * join_f32(h4.z, l4.z) + kvs[d+3] * join_f32(h4.w, l4.w);
            }
            sv[t] = ck2[c] - 2.f * s;
        }
        __syncthreads();

        unsigned prefix = 0;
        int plen = 0;
        int nd = need;
        for (int pass = 0; pass < 4; ++pass) {
            const int shift = 24 - 8 * pass;
            hist[tid] = 0;
            __syncthreads();
            for (int t = tid; t < T; t += 256) {
                const unsigned u = f2u_mono(sv[t]);
                if (plen == 0 || (u >> (32 - plen)) == prefix)
                    atomicAdd(&hist[(u >> shift) & 255u], 1u);
            }
            __syncthreads();
            if (tid == 0) {
                int cum = 0;
                for (int bb = 0; bb < 256; ++bb) {
                    const int h = (int)hist[bb];
                    if (cum + h >= nd) { sh_bin = (unsigned)bb; sh_need = (unsigned)(nd - cum); break; }
                    cum += h;
                }
            }
            __syncthreads();
            prefix = (prefix << 8) | sh_bin;
            nd = (int)sh_need;
            plen += 8;
            __syncthreads();
        }
        const unsigned Tf = prefix;
        const int nl2 = need - nd;
        if (tid == 0) { c1 = 0; c2 = 0; }
        __syncthreads();
        for (int t = tid; t < T; t += 256) {
            const unsigned u = f2u_mono(sv[t]);
            if (u < Tf) {
                const int p = atomicAdd(&c1, 1);
                sel[less + p] = tiebuf[(size_t)row * MAXTIE + t];
                idx_out[row * CTX + less + p] = sel[less + p];
            } else if (u == Tf) {
                const int p = atomicAdd(&c2, 1);
                if (p < nd) {
                    sel[less + nl2 + p] = tiebuf[(size_t)row * MAXTIE + t];
                    idx_out[row * CTX + less + nl2 + p] = sel[less + nl2 + p];
                }
            }
        }
    }
    __syncthreads();

    const int wv = tid >> 6, lane = tid & 63;
    for (int c = wv; c < CTX; c += 4) {
        const int id = sel[c];
        const ushort4 h4 = *(const ushort4*)(ckh + (size_t)id * D_MAIN + lane * 4);
        const ushort4 l4 = *(const ushort4*)(ckl + (size_t)id * D_MAIN + lane * 4);
        float s = kvs[lane*4+0] * join_f32(h4.x, l4.x)
                + kvs[lane*4+1] * join_f32(h4.y, l4.y)
                + kvs[lane*4+2] * join_f32(h4.z, l4.z)
                + kvs[lane*4+3] * join_f32(h4.w, l4.w);
        #pragma unroll
        for (int off = 32; off; off >>= 1) s += __shfl_down(s, off, 64);
        if (lane == 0) svals[c] = ck2[id] - 2.f * s;
    }
    __syncthreads();

    if (tid < 128) {
        const float v = (tid < CTX) ? -svals[tid] : -1e30f;
        red[tid] = v;
        __builtin_amdgcn_s_barrier();
    }
    __syncthreads();
    if (tid < 128) {
        for (int s = 64; s > 0; s >>= 1) {
            if (tid < s) red[tid] = fmaxf(red[tid], red[tid + s]);
            __builtin_amdgcn_s_barrier();
        }
    }
    __syncthreads();
    const float mx = red[0];
    __syncthreads();
    float e = 0.f;
    if (tid < 128) {
        e = (tid < CTX) ? __expf(-svals[tid] - mx) : 0.f;
        red[tid] = e;
    }
    __syncthreads();
    if (tid < 128) {
        for (int s = 64; s > 0; s >>= 1) {
            if (tid < s) red[tid] += red[tid + s];
            __builtin_amdgcn_s_barrier();
        }
    }
    __syncthreads();
    if (tid < CTX) probs[row * CTX + tid] = e / red[0];
}

// ---------------------------------------------------------------------------
// h[b,d] += sum_c probs[b,c] * (label_emb[cand_y[idx[b,c]], d] + v[(b,c), d])
// ---------------------------------------------------------------------------
__global__ __launch_bounds__(256)
void mix_reduce_kernel(float* __restrict__ h, const float* __restrict__ v,
                       const float* __restrict__ probs, const int* __restrict__ idx,
                       const int* __restrict__ cy, const float* __restrict__ label_emb)
{
    const int b = blockIdx.x;
    const int d = threadIdx.x;
    float acc = 0.f;
    for (int c = 0; c < CTX; ++c) {
        const int bc = b * CTX + c;
        const int id = idx[bc];
        const int y = cy[id];
        const float val = label_emb[(size_t)y * D_MAIN + d] + v[(size_t)bc * D_MAIN + d];
        acc = fmaf(probs[bc], val, acc);
    }
    h[(size_t)b * D_MAIN + d] += acc;
}

// ---------------------------------------------------------------------------
// host-side orchestration
// ---------------------------------------------------------------------------
static inline dim3 g128(int M, int N) {
    return dim3((unsigned)((N + 127) / 128), (unsigned)((M + 127) / 128));
}

struct EncW {
    const u16 *WlinTh, *WlinTl, *e0W1Th, *e0W1Tl, *e0W2Th, *e0W2Tl,
              *e1W1Th, *e1W1Tl, *e1W2Th, *e1W2Tl, *KWTh, *KWTl;
    const float *b_lin, *e0b1, *e0b2, *e1g, *e1b, *e1b1, *e1b2, *mixg, *mixb, *Kb;
};

// Encoder: full split x split (3 MFMA); H residual stream kept split-only
// (ping-pong H0/H1 split buffers; residual reads join in epilogue).
static void encode_rows_split(const u16* Xh, const u16* Xl, int R, const EncW& w,
                              u16* H0h, u16* H0l, u16* H1h, u16* H1l,
                              u16* Th, u16* Tl, u16* TNh, u16* TNl,
                              u16* Kh, u16* Kl, hipStream_t stream)
{
    dim3 blk(256);
    // Wlin -> H0 (split only)
    gemm_split_nt<false,true,false,false,false, false,true,false, true,true,false><<<g128(R, D_MAIN), blk, 0, stream>>>(
        Xh, Xl, w.WlinTh, w.WlinTl, w.b_lin, nullptr, nullptr, nullptr,
        nullptr, H0h, H0l, R, D_MAIN, D_IN);
    // e0W1: relu(H0 @ W1 + b1) -> T
    gemm_split_nt<true,true,false,false,false, false,true,false, true,true,false><<<g128(R, D_BLOCK), blk, 0, stream>>>(
        H0h, H0l, w.e0W1Th, w.e0W1Tl, w.e0b1, nullptr, nullptr, nullptr,
        nullptr, Th, Tl, R, D_BLOCK, D_MAIN);
    // e0W2: T @ W2 + b2 + H0 -> H1
    gemm_split_nt<false,true,true,true,false, false,true,false, true,true,false><<<g128(R, D_MAIN), blk, 0, stream>>>(
        Th, Tl, w.e0W2Th, w.e0W2Tl, w.e0b2, nullptr, H0h, H0l,
        nullptr, H1h, H1l, R, D_MAIN, D_BLOCK);
    // LN(H1) -> TN
    ln_kernel<false,true,true><<<R, 256, 0, stream>>>(nullptr, H1h, H1l, w.e1g, w.e1b,
                                                      nullptr, TNh, TNl);
    // e1W1: relu(TN @ W1 + b1) -> T
    gemm_split_nt<true,true,false,false,false, false,true,false, true,true,false><<<g128(R, D_BLOCK), blk, 0, stream>>>(
        TNh, TNl, w.e1W1Th, w.e1W1Tl, w.e1b1, nullptr, nullptr, nullptr,
        nullptr, Th, Tl, R, D_BLOCK, D_MAIN);
    // e1W2: T @ W2 + b2 + H1 -> H0 (final h)
    gemm_split_nt<false,true,true,true,false, false,true,false, true,true,false><<<g128(R, D_MAIN), blk, 0, stream>>>(
        Th, Tl, w.e1W2Th, w.e1W2Tl, w.e1b2, nullptr, H1h, H1l,
        nullptr, H0h, H0l, R, D_MAIN, D_BLOCK);
    // LN(H0) -> TN
    ln_kernel<false,true,true><<<R, 256, 0, stream>>>(nullptr, H0h, H0l, w.mixg, w.mixb,
                                                      nullptr, TNh, TNl);
    // K = TN @ KW + Kb -> split
    gemm_split_nt<false,true,false,false,false, false,true,false, true,true,false><<<g128(R, D_MAIN), blk, 0, stream>>>(
        TNh, TNl, w.KWTh, w.KWTl, w.Kb, nullptr, nullptr, nullptr,
        nullptr, Kh, Kl, R, D_MAIN, D_MAIN);
}

extern "C" void kernel_launch(void* const* d_in, const int* in_sizes, int n_in,
                              void* d_out, int out_size, void* d_ws, size_t ws_size,
                              hipStream_t stream)
{
    const float* x        = (const float*)d_in[0];
    const float* cand_x   = (const float*)d_in[1];
    const int*   cand_y   = (const int*)  d_in[2];
    const float* W_lin    = (const float*)d_in[4];
    const float* b_lin    = (const float*)d_in[5];
    const float* e0W1     = (const float*)d_in[6];
    const float* e0b1     = (const float*)d_in[7];
    const float* e0W2     = (const float*)d_in[8];
    const float* e0b2     = (const float*)d_in[9];
    const float* e1g      = (const float*)d_in[10];
    const float* e1b      = (const float*)d_in[11];
    const float* e1W1     = (const float*)d_in[12];
    const float* e1b1     = (const float*)d_in[13];
    const float* e1W2     = (const float*)d_in[14];
    const float* e1b2     = (const float*)d_in[15];
    const float* mixg     = (const float*)d_in[16];
    const float* mixb     = (const float*)d_in[17];
    const float* K_W      = (const float*)d_in[18];
    const float* K_b      = (const float*)d_in[19];
    const float* label_emb= (const float*)d_in[20];
    const float* T_W1     = (const float*)d_in[21];
    const float* T_b1     = (const float*)d_in[22];
    const float* T_W2     = (const float*)d_in[23];
    const float* p0g      = (const float*)d_in[24];
    const float* p0b      = (const float*)d_in[25];
    const float* p0W1     = (const float*)d_in[26];
    const float* p0b1     = (const float*)d_in[27];
    const float* p0W2     = (const float*)d_in[28];
    const float* p0b2     = (const float*)d_in[29];
    const float* p1g      = (const float*)d_in[30];
    const float* p1b      = (const float*)d_in[31];
    const float* p1W1     = (const float*)d_in[32];
    const float* p1b1     = (const float*)d_in[33];
    const float* p1W2     = (const float*)d_in[34];
    const float* p1b2     = (const float*)d_in[35];
    const float* headg    = (const float*)d_in[36];
    const float* headb    = (const float*)d_in[37];
    const float* head_W   = (const float*)d_in[38];
    const float* head_bias= (const float*)d_in[39];

    char* ws = (char*)d_ws;
    size_t off = 0;
    auto alloc = [&](size_t bytes) -> char* {
        char* p = ws + off;
        off += (bytes + 255) & ~(size_t)255;
        return p;
    };

    u16* in_h   = (u16*)alloc((size_t)NTOT * D_IN * 2);
    u16* in_l   = (u16*)alloc((size_t)NTOT * D_IN * 2);
    u16* allk_h = (u16*)alloc((size_t)NTOT * D_MAIN * 2);
    u16* allk_l = (u16*)alloc((size_t)NTOT * D_MAIN * 2);
    float* ck2  = (float*)alloc((size_t)N_CAND * 4);
    float* h_x  = (float*)alloc((size_t)B_ROWS * D_MAIN * 4);
    float* tn_x = (float*)alloc((size_t)B_ROWS * D_MAIN * 4);
    float* t_x  = (float*)alloc((size_t)B_ROWS * D_BLOCK * 4);
    int*   idx  = (int*)  alloc((size_t)B_ROWS * CTX * 4);
    float* probs= (float*)alloc((size_t)B_ROWS * CTX * 4);
    int* tiebuf = (int*)  alloc((size_t)B_ROWS * MAXTIE * 4);
    int* tiecnt = (int*)  alloc((size_t)B_ROWS * 4);
    int* lesscnt= (int*)  alloc((size_t)B_ROWS * 4);

    u16* WlinTh = (u16*)alloc((size_t)D_IN  * D_MAIN * 2);
    u16* WlinTl = (u16*)alloc((size_t)D_IN  * D_MAIN * 2);
    u16* e0W1Th = (u16*)alloc((size_t)D_MAIN* D_BLOCK * 2);
    u16* e0W1Tl = (u16*)alloc((size_t)D_MAIN* D_BLOCK * 2);
    u16* e0W2Th = (u16*)alloc((size_t)D_BLOCK*D_MAIN * 2);
    u16* e0W2Tl = (u16*)alloc((size_t)D_BLOCK*D_MAIN * 2);
    u16* e1W1Th = (u16*)alloc((size_t)D_MAIN* D_BLOCK * 2);
    u16* e1W1Tl = (u16*)alloc((size_t)D_MAIN* D_BLOCK * 2);
    u16* e1W2Th = (u16*)alloc((size_t)D_BLOCK*D_MAIN * 2);
    u16* e1W2Tl = (u16*)alloc((size_t)D_BLOCK*D_MAIN * 2);
    u16* KWTh   = (u16*)alloc((size_t)D_MAIN* D_MAIN * 2);
    u16* KWTl   = (u16*)alloc((size_t)D_MAIN* D_MAIN * 2);
    u16* TW1Th  = (u16*)alloc((size_t)D_MAIN* D_BLOCK * 2);
    u16* TW1Tl  = (u16*)alloc((size_t)D_MAIN* D_BLOCK * 2);
    u16* TW2Th  = (u16*)alloc((size_t)D_BLOCK*D_MAIN * 2);
    u16* TW2Tl  = (u16*)alloc((size_t)D_BLOCK*D_MAIN * 2);

    u16* k_x_h = allk_h + (size_t)N_CAND * D_MAIN;
    u16* k_x_l = allk_l + (size_t)N_CAND * D_MAIN;
    u16* x_in_h = in_h + (size_t)N_CAND * D_IN;
    u16* x_in_l = in_l + (size_t)N_CAND * D_IN;

    const size_t pool_avail = (ws_size > off) ? (ws_size - off) : 0;
    // per row: H0(1024) + H1(1024) + T(2048) + TN(1024) = 5120 B
    int rc_enc = (int)(pool_avail / 5120);
    if (rc_enc > NTOT) rc_enc = NTOT;
    if (rc_enc < 6250) rc_enc = 6250;
    int mb_ch = (int)(pool_avail / ((size_t)2 * N_CAND));
    if (mb_ch > B_ROWS) mb_ch = B_ROWS;
    mb_ch &= ~127;
    if (mb_ch < 128)    mb_ch = 128;
    int bb_ch = (int)(pool_avail / ((size_t)CTX * 2048));
    if (bb_ch > B_ROWS) bb_ch = B_ROWS;
    if (bb_ch < 64)     bb_ch = 64;

    char* pool = ws + off;
    dim3 blk(256);

    // 0) conversions
    {
        f32_to_split_kernel<<<(N_CAND*D_IN + 255)/256, blk, 0, stream>>>(cand_x, in_h, in_l, N_CAND*D_IN);
        f32_to_split_kernel<<<(B_ROWS*D_IN + 255)/256, blk, 0, stream>>>(x, x_in_h, x_in_l, B_ROWS*D_IN);
        TrD8 tr;
        tr.d[0] = { W_lin, WlinTh, WlinTl, D_IN,   D_MAIN };
        tr.d[1] = { e0W1,  e0W1Th, e0W1Tl, D_MAIN, D_BLOCK };
        tr.d[2] = { e0W2,  e0W2Th, e0W2Tl, D_BLOCK,D_MAIN };
        tr.d[3] = { e1W1,  e1W1Th, e1W1Tl, D_MAIN, D_BLOCK };
        tr.d[4] = { e1W2,  e1W2Th, e1W2Tl, D_BLOCK,D_MAIN };
        tr.d[5] = { K_W,   KWTh,   KWTl,   D_MAIN, D_MAIN };
        tr.d[6] = { T_W1,  TW1Th,  TW1Tl,  D_MAIN, D_BLOCK };
        tr.d[7] = { T_W2,  TW2Th,  TW2Tl,  D_BLOCK,D_MAIN };
        transpose_all_kernel<<<dim3(512, 8), blk, 0, stream>>>(tr);
    }

    EncW w = { WlinTh, WlinTl, e0W1Th, e0W1Tl, e0W2Th, e0W2Tl,
               e1W1Th, e1W1Tl, e1W2Th, e1W2Tl, KWTh, KWTl,
               b_lin, e0b1, e0b2, e1g, e1b, e1b1, e1b2, mixg, mixb, K_b };

    // 1) combined encode (candidates + x); final h kept in H0 (split)
    for (int r0 = 0; r0 < NTOT; r0 += rc_enc) {
        const int R = (NTOT - r0 < rc_enc) ? (NTOT - r0) : rc_enc;
        char* p = pool;
        u16* H0h = (u16*)p;           p += (size_t)rc_enc * D_MAIN * 2;
        u16* H0l = (u16*)p;           p += (size_t)rc_enc * D_MAIN * 2;
        u16* H1h = (u16*)p;           p += (size_t)rc_enc * D_MAIN * 2;
        u16* H1l = (u16*)p;           p += (size_t)rc_enc * D_MAIN * 2;
        u16* Th  = (u16*)p;           p += (size_t)rc_enc * D_BLOCK * 2;
        u16* Tl  = (u16*)p;           p += (size_t)rc_enc * D_BLOCK * 2;
        u16* TNh = (u16*)p;           p += (size_t)rc_enc * D_MAIN * 2;
        u16* TNl = (u16*)p;
        encode_rows_split(in_h + (size_t)r0 * D_IN, in_l + (size_t)r0 * D_IN,
                          R, w, H0h, H0l, H1h, H1l, Th, Tl, TNh, TNl,
                          allk_h + (size_t)r0 * D_MAIN,
                          allk_l + (size_t)r0 * D_MAIN, stream);
        const int lo = (r0 > N_CAND) ? r0 : N_CAND;
        const int hi = (r0 + R < NTOT) ? r0 + R : NTOT;
        if (lo < hi) {
            const int n = (hi - lo) * D_MAIN;
            join_rows_kernel<<<(n + 255)/256, blk, 0, stream>>>(
                H0h + (size_t)(lo - r0) * D_MAIN, H0l + (size_t)(lo - r0) * D_MAIN,
                h_x + (size_t)(lo - N_CAND) * D_MAIN, n);
        }
    }

    // 2) candidate norms
    cn2_kernel<<<N_CAND, 64, 0, stream>>>(allk_h, allk_l, ck2);

    // 3+4) distance keys (bf16-hi only) + top-96 select
    for (int m0 = 0; m0 < B_ROWS; m0 += mb_ch) {
        const int R = (B_ROWS - m0 < mb_ch) ? (B_ROWS - m0) : mb_ch;
        u16* s_keys = (u16*)pool;
        dim3 grid((unsigned)((R + 127) / 128), (unsigned)((N_CAND + 127) / 128));
        gemm_split_nt<false,false,false,false,true, false,false,false, false,false,true><<<grid, blk, 0, stream>>>(
            k_x_h + (size_t)m0 * D_MAIN, nullptr,
            allk_h, nullptr, ck2, nullptr, nullptr, nullptr,
            nullptr, s_keys, nullptr, R, N_CAND, D_MAIN);
        topk96_u16_kernel<<<R, 1024, 0, stream>>>(
            s_keys, idx + m0 * CTX, tiebuf + (size_t)m0 * MAXTIE,
            tiecnt + m0, lesscnt + m0);
    }

    // 5) fused exact tie-break + sval + softmax
    select_kernel<<<B_ROWS, 256, 0, stream>>>(k_x_h, k_x_l, allk_h, allk_l, ck2,
                                              tiebuf, tiecnt, lesscnt, idx, probs);

    // 6) T-MLP (GEMM1 fused gather, split A; GEMM2 A hi x split W2) + mix
    for (int b0 = 0; b0 < B_ROWS; b0 += bb_ch) {
        const int rows = (B_ROWS - b0 < bb_ch) ? (B_ROWS - b0) : bb_ch;
        const int R = rows * CTX;
        char* p = pool;
        u16* th = (u16*)p;  p += (size_t)bb_ch * CTX * D_BLOCK * 2;
        float* v = (float*)p;
        gemm_tmlp1<<<g128(R, D_BLOCK), blk, 0, stream>>>(
            k_x_h, k_x_l, allk_h, allk_l, idx + b0 * CTX, b0,
            TW1Th, TW1Tl, T_b1, th, R, D_BLOCK, D_MAIN);
        gemm_split_nt<false,false,false,false,false, true,false,false, false,true,false><<<g128(R, D_MAIN), blk, 0, stream>>>(
            th, nullptr, TW2Th, TW2Tl, nullptr, nullptr, nullptr, nullptr,
            v, nullptr, nullptr, R, D_MAIN, D_BLOCK);
        mix_reduce_kernel<<<rows, 256, 0, stream>>>(
            h_x + (size_t)b0 * D_MAIN, v, probs + b0 * CTX, idx + b0 * CTX,
            cand_y, label_emb);
    }

    // 7) post blocks (fp32)
    ln_kernel<false,false,false><<<B_ROWS, 256, 0, stream>>>(h_x, nullptr, nullptr, p0g, p0b, tn_x, nullptr, nullptr);
    gemm128<true, true,false><<<g128(B_ROWS, D_BLOCK), blk, 0, stream>>>(tn_x, p0W1, p0b1, nullptr, t_x, B_ROWS, D_BLOCK, D_MAIN);
    gemm128<false,true,true ><<<g128(B_ROWS, D_MAIN), blk, 0, stream>>>(t_x, p0W2, p0b2, h_x, h_x, B_ROWS, D_MAIN, D_BLOCK);
    ln_kernel<false,false,false><<<B_ROWS, 256, 0, stream>>>(h_x, nullptr, nullptr, p1g, p1b, tn_x, nullptr, nullptr);
    gemm128<true, true,false><<<g128(B_ROWS, D_BLOCK), blk, 0, stream>>>(tn_x, p1W1, p1b1, nullptr, t_x, B_ROWS, D_BLOCK, D_MAIN);
    gemm128<false,true,true ><<<g128(B_ROWS, D_MAIN), blk, 0, stream>>>(t_x, p1W2, p1b2, h_x, h_x, B_ROWS, D_MAIN, D_BLOCK);

    // 8) head (fp32)
    ln_kernel<true,false,false><<<B_ROWS, 256, 0, stream>>>(h_x, nullptr, nullptr, headg, headb, tn_x, nullptr, nullptr);
    gemm_head<<<dim3(1, (B_ROWS + 63) / 64), blk, 0, stream>>>(
        tn_x, head_W, head_bias, (float*)d_out, B_ROWS, N_OUT, D_MAIN);
}

// Round 14
// 1511.224 us; speedup vs baseline: 1.2563x; 1.2563x over previous
//
#include <hip/hip_runtime.h>
#include <hip/hip_bf16.h>
#include <cstdint>
#include <cstddef>

#define B_ROWS 1024
#define N_CAND 50000
#define CTX    96
#define D_IN   128
#define D_MAIN 256
#define D_BLOCK 512
#define N_OUT  10
#define LN_EPS 1e-5f
#define MAXTIE 4096
#define NTOT   (N_CAND + B_ROWS)

typedef unsigned short u16;
typedef __attribute__((ext_vector_type(8))) short bf16x8;
typedef __attribute__((ext_vector_type(4))) float f32x4;

__device__ __forceinline__ u16 bf16_bits(float f) {
    __hip_bfloat16 h = __float2bfloat16(f);
    return *reinterpret_cast<u16*>(&h);
}
__device__ __forceinline__ float bits_to_f32(u16 b) {
    unsigned u = ((unsigned)b) << 16;
    return __uint_as_float(u);
}
__device__ __forceinline__ void split_f32(float v, u16& h, u16& l) {
    h = bf16_bits(v);
    l = bf16_bits(v - bits_to_f32(h));
}
__device__ __forceinline__ float join_f32(u16 h, u16 l) {
    return bits_to_f32(h) + bits_to_f32(l);
}
__device__ __forceinline__ unsigned f2u_mono(float f) {
    unsigned u = __float_as_uint(f);
    return u ^ ((u & 0x80000000u) ? 0xFFFFFFFFu : 0x80000000u);
}

__device__ __forceinline__ void load_lds_16B(const void* gp, void* lp) {
    __builtin_amdgcn_global_load_lds((const __attribute__((address_space(1))) void*)gp,
                                     (__attribute__((address_space(3))) void*)lp,
                                     16, 0, 0);
}

// ---------------------------------------------------------------------------
// Split-bf16 MFMA GEMM (NT). 128x128 tile, BK=32, 256 threads, 16x16x32 MFMA.
// acc += AhBh (+AlBh if A_LO) (+AhBl if B_LO).
// KEY16: u16 monotone key of (-2*acc+bias) -> Ch (staged LDS store).
// OUT_SPLIT: (Ch,Cl).  OUT_B16: Ch bf16.  OUT_F32: Cf.  MXFAST: m on blockIdx.x
// ---------------------------------------------------------------------------
template<bool RELU, bool HAS_BIAS, bool HAS_RES, bool KEY16,
         bool OUT_F32, bool OUT_SPLIT, bool OUT_B16, bool A_LO, bool B_LO, bool MXFAST>
__global__ __launch_bounds__(256)
void gemm_split_nt(const u16* __restrict__ Ah, const u16* __restrict__ Al,
                   const u16* __restrict__ Bh, const u16* __restrict__ Bl,
                   const float* __restrict__ bias, const float* __restrict__ Rm,
                   float* __restrict__ Cf, u16* __restrict__ Ch, u16* __restrict__ Cl,
                   int M, int N, int K)
{
    constexpr int N_LOAD = (2 + (A_LO ? 1 : 0) + (B_LO ? 1 : 0)) * 4096;
    constexpr bool STAGED = KEY16 || OUT_SPLIT || OUT_B16;
    constexpr int SM_U16 = (STAGED && N_LOAD < 16384) ? 16384 : N_LOAD;
    __shared__ __align__(16) u16 smem[SM_U16];
    u16* Ash = smem;
    u16* Asl = A_LO ? smem + 4096 : smem;
    u16* Bsh = smem + 4096 * (1 + (A_LO ? 1 : 0));
    u16* Bsl = B_LO ? Bsh + 4096 : Bsh;

    const int tid  = threadIdx.x;
    const int wave = tid >> 6, lane = tid & 63;
    const int bm = (MXFAST ? blockIdx.x : blockIdx.y) * 128;
    const int bn = (MXFAST ? blockIdx.y : blockIdx.x) * 128;
    const int wm = (wave >> 1) * 64, wn = (wave & 1) * 64;
    const int l16 = lane & 15, quad = lane >> 4;

    const int srow = lane >> 2;
    const int scol = (lane & 3) * 8;

    f32x4 acc[4][4];
    #pragma unroll
    for (int i = 0; i < 4; ++i)
        #pragma unroll
        for (int j = 0; j < 4; ++j)
            acc[i][j] = (f32x4){0.f, 0.f, 0.f, 0.f};

    for (int k0 = 0; k0 < K; k0 += 32) {
        const int r0 = wave * 16 + srow, r1 = r0 + 64;
        int ga0 = bm + r0; if (ga0 > M - 1) ga0 = M - 1;
        int ga1 = bm + r1; if (ga1 > M - 1) ga1 = M - 1;
        int gb0 = bn + r0; if (gb0 > N - 1) gb0 = N - 1;
        int gb1 = bn + r1; if (gb1 > N - 1) gb1 = N - 1;
        const size_t a0 = (size_t)ga0 * K + k0 + scol;
        const size_t a1 = (size_t)ga1 * K + k0 + scol;
        const size_t b0 = (size_t)gb0 * K + k0 + scol;
        const size_t b1 = (size_t)gb1 * K + k0 + scol;

        load_lds_16B(Ah + a0, &Ash[(wave * 16) * 32]);
        load_lds_16B(Ah + a1, &Ash[(64 + wave * 16) * 32]);
        if constexpr (A_LO) {
            load_lds_16B(Al + a0, &Asl[(wave * 16) * 32]);
            load_lds_16B(Al + a1, &Asl[(64 + wave * 16) * 32]);
        }
        load_lds_16B(Bh + b0, &Bsh[(wave * 16) * 32]);
        load_lds_16B(Bh + b1, &Bsh[(64 + wave * 16) * 32]);
        if constexpr (B_LO) {
            load_lds_16B(Bl + b0, &Bsl[(wave * 16) * 32]);
            load_lds_16B(Bl + b1, &Bsl[(64 + wave * 16) * 32]);
        }
        __syncthreads();

        bf16x8 ah[4], al[4], bh[4], bl[4];
        #pragma unroll
        for (int i = 0; i < 4; ++i) {
            ah[i] = *(const bf16x8*)&Ash[(wm + i * 16 + l16) * 32 + quad * 8];
            if constexpr (A_LO)
                al[i] = *(const bf16x8*)&Asl[(wm + i * 16 + l16) * 32 + quad * 8];
        }
        #pragma unroll
        for (int j = 0; j < 4; ++j) {
            bh[j] = *(const bf16x8*)&Bsh[(wn + j * 16 + l16) * 32 + quad * 8];
            if constexpr (B_LO)
                bl[j] = *(const bf16x8*)&Bsl[(wn + j * 16 + l16) * 32 + quad * 8];
        }

        #pragma unroll
        for (int i = 0; i < 4; ++i)
            #pragma unroll
            for (int j = 0; j < 4; ++j) {
                acc[i][j] = __builtin_amdgcn_mfma_f32_16x16x32_bf16(ah[i], bh[j], acc[i][j], 0, 0, 0);
                if constexpr (A_LO)
                    acc[i][j] = __builtin_amdgcn_mfma_f32_16x16x32_bf16(al[i], bh[j], acc[i][j], 0, 0, 0);
                if constexpr (B_LO)
                    acc[i][j] = __builtin_amdgcn_mfma_f32_16x16x32_bf16(ah[i], bl[j], acc[i][j], 0, 0, 0);
            }
        __syncthreads();
    }

    float bvj[4];
    #pragma unroll
    for (int j = 0; j < 4; ++j) {
        const int n = bn + wn + j * 16 + l16;
        bvj[j] = ((HAS_BIAS || KEY16) && n < N) ? bias[n] : 0.f;
    }
    auto compute = [&](int i, int j, int r) -> float {
        float v = acc[i][j][r];
        if (KEY16) return -2.f * v + bvj[j];
        if (HAS_BIAS) v += bvj[j];
        if (RELU)     v = fmaxf(v, 0.f);
        if (HAS_RES) {
            const int n = bn + wn + j * 16 + l16;
            const int m = bm + wm + i * 16 + quad * 4 + r;
            v += Rm[(size_t)m * N + n];
        }
        return v;
    };

    if constexpr (OUT_F32) {
        #pragma unroll
        for (int j = 0; j < 4; ++j) {
            const int n = bn + wn + j * 16 + l16;
            if (n >= N) continue;
            #pragma unroll
            for (int i = 0; i < 4; ++i)
                #pragma unroll
                for (int r = 0; r < 4; ++r) {
                    const int m = bm + wm + i * 16 + quad * 4 + r;
                    if (m >= M) continue;
                    Cf[(size_t)m * N + n] = compute(i, j, r);
                }
        }
    }

    if constexpr (STAGED) {
        u16* Cs = smem;
        const int phases = OUT_SPLIT ? 2 : 1;
        for (int ph = 0; ph < phases; ++ph) {
            __syncthreads();
            #pragma unroll
            for (int j = 0; j < 4; ++j) {
                const int nl = wn + j * 16 + l16;
                if (bn + nl >= N) continue;
                #pragma unroll
                for (int i = 0; i < 4; ++i)
                    #pragma unroll
                    for (int r = 0; r < 4; ++r) {
                        const int ml = wm + i * 16 + quad * 4 + r;
                        if (bm + ml >= M) continue;
                        const float v = compute(i, j, r);
                        u16 out;
                        if (KEY16)        out = (u16)(f2u_mono(v) >> 16);
                        else if (OUT_B16) out = bf16_bits(v);
                        else { u16 h, l; split_f32(v, h, l); out = ph ? l : h; }
                        Cs[ml * 128 + nl] = out;
                    }
            }
            __syncthreads();
            u16* dstB = (OUT_SPLIT && ph) ? Cl : Ch;
            const int row = tid >> 1, seg = (tid & 1) * 64;
            const int m = bm + row;
            if (m < M) {
                const int ncols = N - bn;
                u16* dst = dstB + (size_t)m * N + bn + seg;
                const u16* srcp = &Cs[row * 128 + seg];
                if (ncols >= 128) {
                    #pragma unroll
                    for (int c = 0; c < 8; ++c)
                        *reinterpret_cast<uint4*>(dst + c * 8) =
                            *reinterpret_cast<const uint4*>(srcp + c * 8);
                } else {
                    for (int e = 0; e < 64; ++e)
                        if (seg + e < ncols) dst[e] = srcp[e];
                }
            }
        }
    }
}

// ---------------------------------------------------------------------------
// T-MLP GEMM1 with fused diff gather (R10-proven: split A, 3 MFMA):
//   A[bc,k] = split(k_x[b] - cand_k[idx[bc]]);  C = bf16(relu(A@B^T + bias))
// ---------------------------------------------------------------------------
__global__ __launch_bounds__(256)
void gemm_tmlp1(const u16* __restrict__ kh, const u16* __restrict__ kl,
                const u16* __restrict__ ckh, const u16* __restrict__ ckl,
                const int* __restrict__ idx, int b_base,
                const u16* __restrict__ Bh, const u16* __restrict__ Bl,
                const float* __restrict__ bias, u16* __restrict__ Ch,
                int M, int N, int K)
{
    __shared__ __align__(16) u16 smem[16384];
    u16* Ash = smem;
    u16* Asl = smem + 4096;
    u16* Bsh = smem + 8192;
    u16* Bsl = smem + 12288;

    const int tid  = threadIdx.x;
    const int wave = tid >> 6, lane = tid & 63;
    const int bm = blockIdx.y * 128, bn = blockIdx.x * 128;
    const int wm = (wave >> 1) * 64, wn = (wave & 1) * 64;
    const int l16 = lane & 15, quad = lane >> 4;
    const int srow = lane >> 2, scol = (lane & 3) * 8;

    const int rowA = tid >> 1;
    const int c0 = (tid & 1) * 16;
    int bcl = bm + rowA; if (bcl > M - 1) bcl = M - 1;
    const int brow = b_base + bcl / CTX;
    const int id = idx[bcl];
    const u16* kph = kh + (size_t)brow * D_MAIN;
    const u16* kpl = kl + (size_t)brow * D_MAIN;
    const u16* cph = ckh + (size_t)id * D_MAIN;
    const u16* cpl = ckl + (size_t)id * D_MAIN;

    f32x4 acc[4][4];
    #pragma unroll
    for (int i = 0; i < 4; ++i)
        #pragma unroll
        for (int j = 0; j < 4; ++j)
            acc[i][j] = (f32x4){0.f, 0.f, 0.f, 0.f};

    for (int k0 = 0; k0 < K; k0 += 32) {
        {
            const int c = k0 + c0;
            __align__(16) u16 th[16], tl[16];
            #pragma unroll
            for (int g = 0; g < 4; ++g) {
                const ushort4 a  = *(const ushort4*)(kph + c + g * 4);
                const ushort4 b_ = *(const ushort4*)(kpl + c + g * 4);
                const ushort4 cc = *(const ushort4*)(cph + c + g * 4);
                const ushort4 dd = *(const ushort4*)(cpl + c + g * 4);
                const float d0 = join_f32(a.x, b_.x) - join_f32(cc.x, dd.x);
                const float d1 = join_f32(a.y, b_.y) - join_f32(cc.y, dd.y);
                const float d2 = join_f32(a.z, b_.z) - join_f32(cc.z, dd.z);
                const float d3 = join_f32(a.w, b_.w) - join_f32(cc.w, dd.w);
                split_f32(d0, th[g*4+0], tl[g*4+0]);
                split_f32(d1, th[g*4+1], tl[g*4+1]);
                split_f32(d2, th[g*4+2], tl[g*4+2]);
                split_f32(d3, th[g*4+3], tl[g*4+3]);
            }
            *(uint4*)&Ash[rowA * 32 + c0]     = *(const uint4*)&th[0];
            *(uint4*)&Ash[rowA * 32 + c0 + 8] = *(const uint4*)&th[8];
            *(uint4*)&Asl[rowA * 32 + c0]     = *(const uint4*)&tl[0];
            *(uint4*)&Asl[rowA * 32 + c0 + 8] = *(const uint4*)&tl[8];
        }
        {
            const int r0 = wave * 16 + srow, r1 = r0 + 64;
            int gb0 = bn + r0; if (gb0 > N - 1) gb0 = N - 1;
            int gb1 = bn + r1; if (gb1 > N - 1) gb1 = N - 1;
            const size_t b0 = (size_t)gb0 * K + k0 + scol;
            const size_t b1 = (size_t)gb1 * K + k0 + scol;
            load_lds_16B(Bh + b0, &Bsh[(wave * 16) * 32]);
            load_lds_16B(Bh + b1, &Bsh[(64 + wave * 16) * 32]);
            load_lds_16B(Bl + b0, &Bsl[(wave * 16) * 32]);
            load_lds_16B(Bl + b1, &Bsl[(64 + wave * 16) * 32]);
        }
        __syncthreads();

        bf16x8 ah[4], al[4], bh[4], bl[4];
        #pragma unroll
        for (int i = 0; i < 4; ++i) {
            ah[i] = *(const bf16x8*)&Ash[(wm + i * 16 + l16) * 32 + quad * 8];
            al[i] = *(const bf16x8*)&Asl[(wm + i * 16 + l16) * 32 + quad * 8];
        }
        #pragma unroll
        for (int j = 0; j < 4; ++j) {
            bh[j] = *(const bf16x8*)&Bsh[(wn + j * 16 + l16) * 32 + quad * 8];
            bl[j] = *(const bf16x8*)&Bsl[(wn + j * 16 + l16) * 32 + quad * 8];
        }

        #pragma unroll
        for (int i = 0; i < 4; ++i)
            #pragma unroll
            for (int j = 0; j < 4; ++j) {
                acc[i][j] = __builtin_amdgcn_mfma_f32_16x16x32_bf16(ah[i], bh[j], acc[i][j], 0, 0, 0);
                acc[i][j] = __builtin_amdgcn_mfma_f32_16x16x32_bf16(al[i], bh[j], acc[i][j], 0, 0, 0);
                acc[i][j] = __builtin_amdgcn_mfma_f32_16x16x32_bf16(ah[i], bl[j], acc[i][j], 0, 0, 0);
            }
        __syncthreads();
    }

    float bvj[4];
    #pragma unroll
    for (int j = 0; j < 4; ++j) {
        const int n = bn + wn + j * 16 + l16;
        bvj[j] = (n < N) ? bias[n] : 0.f;
    }

    u16* Cs = smem;
    __syncthreads();
    #pragma unroll
    for (int j = 0; j < 4; ++j) {
        const int nl = wn + j * 16 + l16;
        if (bn + nl >= N) continue;
        #pragma unroll
        for (int i = 0; i < 4; ++i)
            #pragma unroll
            for (int r = 0; r < 4; ++r) {
                const int ml = wm + i * 16 + quad * 4 + r;
                if (bm + ml >= M) continue;
                const float v = fmaxf(acc[i][j][r] + bvj[j], 0.f);
                Cs[ml * 128 + nl] = bf16_bits(v);
            }
    }
    __syncthreads();
    const int row = tid >> 1, seg = (tid & 1) * 64;
    const int m = bm + row;
    if (m < M) {
        u16* dst = Ch + (size_t)m * N + bn + seg;
        const u16* srcp = &Cs[row * 128 + seg];
        #pragma unroll
        for (int c = 0; c < 8; ++c)
            *reinterpret_cast<uint4*>(dst + c * 8) =
                *reinterpret_cast<const uint4*>(srcp + c * 8);
    }
}

// ---------------------------------------------------------------------------
// Small-N fp32 GEMM (head, N=10)
// ---------------------------------------------------------------------------
__global__ __launch_bounds__(256)
void gemm_head(const float* __restrict__ A, const float* __restrict__ Bm,
               const float* __restrict__ bias, float* __restrict__ C,
               int M, int N, int K)
{
    __shared__ float As[16][64];
    __shared__ float Bs[16][64];
    const int tid = threadIdx.x;
    const int bm = blockIdx.y * 64;

    const int a_m = tid >> 2;
    const int a_k = (tid & 3) << 2;
    const int b_k = tid >> 4;
    const int b_n = (tid & 15) << 2;
    const int my = (tid >> 4) << 2;
    const int nx = (tid & 15) << 2;

    float acc[4][4] = {};

    for (int k0 = 0; k0 < K; k0 += 16) {
        float4 av = make_float4(0.f,0.f,0.f,0.f);
        const int gm = bm + a_m;
        if (gm < M) av = *(const float4*)(A + (size_t)gm * K + k0 + a_k);
        As[a_k+0][a_m]=av.x; As[a_k+1][a_m]=av.y; As[a_k+2][a_m]=av.z; As[a_k+3][a_m]=av.w;

        float4 bv = make_float4(0.f,0.f,0.f,0.f);
        const float* bp = Bm + (size_t)(k0 + b_k) * N + b_n;
        if (b_n + 0 < N) bv.x = bp[0];
        if (b_n + 1 < N) bv.y = bp[1];
        if (b_n + 2 < N) bv.z = bp[2];
        if (b_n + 3 < N) bv.w = bp[3];
        *(float4*)&Bs[b_k][b_n] = bv;

        __syncthreads();
        #pragma unroll
        for (int k = 0; k < 16; ++k) {
            const float4 a4 = *(const float4*)&As[k][my];
            const float4 b4 = *(const float4*)&Bs[k][nx];
            const float a[4] = {a4.x,a4.y,a4.z,a4.w};
            const float b[4] = {b4.x,b4.y,b4.z,b4.w};
            #pragma unroll
            for (int i = 0; i < 4; ++i)
                #pragma unroll
                for (int j = 0; j < 4; ++j)
                    acc[i][j] = fmaf(a[i], b[j], acc[i][j]);
        }
        __syncthreads();
    }

    #pragma unroll
    for (int i = 0; i < 4; ++i) {
        const int m = bm + my + i;
        if (m >= M) continue;
        #pragma unroll
        for (int j = 0; j < 4; ++j) {
            const int n = nx + j;
            if (n >= N) continue;
            C[(size_t)m * N + n] = acc[i][j] + bias[n];
        }
    }
}

// ---------------------------------------------------------------------------
// LayerNorm over 256 cols; fp32 input; OUT_SPLIT -> (Yh,Yl) else Yf f32.
// ---------------------------------------------------------------------------
template<bool RELU, bool OUT_SPLIT>
__global__ __launch_bounds__(256)
void ln_kernel(const float* __restrict__ X, const float* __restrict__ g,
               const float* __restrict__ b, float* __restrict__ Yf,
               u16* __restrict__ Yh, u16* __restrict__ Yl)
{
    const int row = blockIdx.x, tid = threadIdx.x;
    const float x = X[(size_t)row * D_MAIN + tid];
    __shared__ float red[4];
    const int lane = tid & 63, wid = tid >> 6;

    float s = x;
    #pragma unroll
    for (int off = 32; off; off >>= 1) s += __shfl_down(s, off, 64);
    if (lane == 0) red[wid] = s;
    __syncthreads();
    const float mean = (red[0] + red[1] + red[2] + red[3]) * (1.f / D_MAIN);
    __syncthreads();

    const float xm = x - mean;
    s = xm * xm;
    #pragma unroll
    for (int off = 32; off; off >>= 1) s += __shfl_down(s, off, 64);
    if (lane == 0) red[wid] = s;
    __syncthreads();
    const float var = (red[0] + red[1] + red[2] + red[3]) * (1.f / D_MAIN);

    float y = xm / sqrtf(var + LN_EPS) * g[tid] + b[tid];
    if (RELU) y = fmaxf(y, 0.f);
    if (OUT_SPLIT) {
        u16 h, l; split_f32(y, h, l);
        Yh[(size_t)row * D_MAIN + tid] = h;
        Yl[(size_t)row * D_MAIN + tid] = l;
    } else {
        Yf[(size_t)row * D_MAIN + tid] = y;
    }
}

// ---------------------------------------------------------------------------
// ||cand_k[n]||^2 from split
// ---------------------------------------------------------------------------
__global__ __launch_bounds__(64)
void cn2_kernel(const u16* __restrict__ ckh, const u16* __restrict__ ckl,
                float* __restrict__ out)
{
    const int row = blockIdx.x, lane = threadIdx.x;
    const ushort4 h4 = *(const ushort4*)(ckh + (size_t)row * D_MAIN + lane * 4);
    const ushort4 l4 = *(const ushort4*)(ckl + (size_t)row * D_MAIN + lane * 4);
    const float c0 = join_f32(h4.x, l4.x), c1 = join_f32(h4.y, l4.y);
    const float c2 = join_f32(h4.z, l4.z), c3 = join_f32(h4.w, l4.w);
    float s = c0*c0 + c1*c1 + c2*c2 + c3*c3;
    #pragma unroll
    for (int off = 32; off; off >>= 1) s += __shfl_down(s, off, 64);
    if (lane == 0) out[row] = s;
}

// ---------------------------------------------------------------------------
// conversions
// ---------------------------------------------------------------------------
__global__ __launch_bounds__(256)
void f32_to_split_kernel(const float* __restrict__ src, u16* __restrict__ hi,
                         u16* __restrict__ lo, int n)
{
    int i = blockIdx.x * 256 + threadIdx.x;
    if (i < n) {
        u16 h, l; split_f32(src[i], h, l);
        hi[i] = h; lo[i] = l;
    }
}

struct TrD { const float* s; u16* dh; u16* dl; int R; int C; };
struct TrD12 { TrD d[12]; };

__global__ __launch_bounds__(256)
void transpose_all_kernel(TrD12 descs)
{
    const TrD D = descs.d[blockIdx.y];
    const int n = D.R * D.C;
    int idx = blockIdx.x * 256 + threadIdx.x;
    if (idx < n) {
        const int r = idx / D.C, c = idx % D.C;
        u16 h, l; split_f32(D.s[idx], h, l);
        D.dh[(size_t)c * D.R + r] = h;
        D.dl[(size_t)c * D.R + r] = l;
    }
}

__global__ __launch_bounds__(256)
void copy_rows_kernel(const float* __restrict__ src, float* __restrict__ dst, int n)
{
    int i = blockIdx.x * 256 + threadIdx.x;
    if (i < n) dst[i] = src[i];
}

// ---------------------------------------------------------------------------
// Top-96 smallest per row on u16 keys; conflict-free hist[bin][64 replicas].
// ---------------------------------------------------------------------------
__global__ __launch_bounds__(1024)
void topk96_u16_kernel(const u16* __restrict__ keys, int* __restrict__ idx_out,
                       int* __restrict__ tiebuf, int* __restrict__ tiecnt,
                       int* __restrict__ lesscnt)
{
    const int row = blockIdx.x;
    const u16* krow = keys + (size_t)row * N_CAND;
    const int tid = threadIdx.x;
    const int rep = tid & 63;

    __shared__ unsigned hist[256 * 64];
    __shared__ unsigned hsum[256];
    __shared__ unsigned sh_bin, sh_need;
    __shared__ int cntLess, cntEq;

    #pragma unroll
    for (int i = 0; i < 16; ++i) hist[tid + i * 1024] = 0;
    __syncthreads();
    for (int i = tid; i < N_CAND / 8; i += 1024) {
        const uint4 v = ((const uint4*)krow)[i];
        const unsigned w[4] = {v.x, v.y, v.z, v.w};
        #pragma unroll
        for (int e = 0; e < 4; ++e) {
            atomicAdd(&hist[(((w[e] >> 8) & 0xFFu)) * 64 + rep], 1u);
            atomicAdd(&hist[((w[e] >> 24)) * 64 + rep], 1u);
        }
    }
    __syncthreads();
    if (tid < 256) {
        unsigned s = 0;
        #pragma unroll
        for (int r = 0; r < 64; ++r) s += hist[tid * 64 + ((r + tid) & 63)];
        hsum[tid] = s;
    }
    __syncthreads();
    int need = CTX;
    if (tid < 64) {
        const unsigned b0 = hsum[tid*4+0], b1 = hsum[tid*4+1],
                       b2 = hsum[tid*4+2], b3 = hsum[tid*4+3];
        const unsigned lsum = b0 + b1 + b2 + b3;
        unsigned pre = lsum;
        #pragma unroll
        for (int off = 1; off < 64; off <<= 1) {
            const unsigned t = __shfl_up(pre, off, 64);
            if (tid >= off) pre += t;
        }
        const unsigned excl = pre - lsum;
        const unsigned nd = (unsigned)need;
        if (excl < nd && excl + lsum >= nd) {
            unsigned bin, rem;
            if      (excl + b0 >= nd)           { bin = tid*4+0; rem = nd - excl; }
            else if (excl + b0 + b1 >= nd)      { bin = tid*4+1; rem = nd - excl - b0; }
            else if (excl + b0 + b1 + b2 >= nd) { bin = tid*4+2; rem = nd - excl - b0 - b1; }
            else                                { bin = tid*4+3; rem = nd - excl - b0 - b1 - b2; }
            sh_bin = bin; sh_need = rem;
        }
    }
    __syncthreads();
    const unsigned hb = sh_bin;
    need = (int)sh_need;
    __syncthreads();

    #pragma unroll
    for (int i = 0; i < 16; ++i) hist[tid + i * 1024] = 0;
    __syncthreads();
    for (int i = tid; i < N_CAND / 8; i += 1024) {
        const uint4 v = ((const uint4*)krow)[i];
        const unsigned w[4] = {v.x, v.y, v.z, v.w};
        #pragma unroll
        for (int e = 0; e < 4; ++e) {
            const unsigned k0 = w[e] & 0xFFFFu, k1 = w[e] >> 16;
            if ((k0 >> 8) == hb) atomicAdd(&hist[(k0 & 255u) * 64 + rep], 1u);
            if ((k1 >> 8) == hb) atomicAdd(&hist[(k1 & 255u) * 64 + rep], 1u);
        }
    }
    __syncthreads();
    if (tid < 256) {
        unsigned s = 0;
        #pragma unroll
        for (int r = 0; r < 64; ++r) s += hist[tid * 64 + ((r + tid) & 63)];
        hsum[tid] = s;
    }
    __syncthreads();
    if (tid < 64) {
        const unsigned b0 = hsum[tid*4+0], b1 = hsum[tid*4+1],
                       b2 = hsum[tid*4+2], b3 = hsum[tid*4+3];
        const unsigned lsum = b0 + b1 + b2 + b3;
        unsigned pre = lsum;
        #pragma unroll
        for (int off = 1; off < 64; off <<= 1) {
            const unsigned t = __shfl_up(pre, off, 64);
            if (tid >= off) pre += t;
        }
        const unsigned excl = pre - lsum;
        const unsigned nd = (unsigned)need;
        if (excl < nd && excl + lsum >= nd) {
            unsigned bin, rem;
            if      (excl + b0 >= nd)           { bin = tid*4+0; rem = nd - excl; }
            else if (excl + b0 + b1 >= nd)      { bin = tid*4+1; rem = nd - excl - b0; }
            else if (excl + b0 + b1 + b2 >= nd) { bin = tid*4+2; rem = nd - excl - b0 - b1; }
            else                                { bin = tid*4+3; rem = nd - excl - b0 - b1 - b2; }
            sh_bin = bin; sh_need = rem;
        }
    }
    __syncthreads();
    const unsigned T16 = (hb << 8) | sh_bin;
    need = (int)sh_need;

    if (tid == 0) { cntLess = 0; cntEq = 0; }
    __syncthreads();

    for (int i = tid; i < N_CAND / 8; i += 1024) {
        const uint4 v = ((const uint4*)krow)[i];
        const unsigned w[4] = {v.x, v.y, v.z, v.w};
        #pragma unroll
        for (int e = 0; e < 4; ++e) {
            const unsigned k0 = w[e] & 0xFFFFu, k1 = w[e] >> 16;
            const int n0 = i * 8 + e * 2, n1 = n0 + 1;
            if (k0 < T16) {
                const int p = atomicAdd(&cntLess, 1);
                idx_out[row * CTX + p] = n0;
            } else if (k0 == T16) {
                const int p = atomicAdd(&cntEq, 1);
                if (p < MAXTIE) tiebuf[(size_t)row * MAXTIE + p] = n0;
            }
            if (k1 < T16) {
                const int p = atomicAdd(&cntLess, 1);
                idx_out[row * CTX + p] = n1;
            } else if (k1 == T16) {
                const int p = atomicAdd(&cntEq, 1);
                if (p < MAXTIE) tiebuf[(size_t)row * MAXTIE + p] = n1;
            }
        }
    }
    __syncthreads();
    if (tid == 0) {
        lesscnt[row] = cntLess;
        tiecnt[row] = (cntEq < MAXTIE) ? cntEq : MAXTIE;
    }
}

// ---------------------------------------------------------------------------
// Fused: exact fp32 tie-break + exact sval for selected 96 + softmax.
// ---------------------------------------------------------------------------
__global__ __launch_bounds__(256)
void select_kernel(const u16* __restrict__ kh, const u16* __restrict__ kl,
                   const u16* __restrict__ ckh, const u16* __restrict__ ckl,
                   const float* __restrict__ ck2,
                   const int* __restrict__ tiebuf, const int* __restrict__ tiecnt,
                   const int* __restrict__ lesscnt,
                   int* __restrict__ idx_out, float* __restrict__ probs)
{
    const int row = blockIdx.x;
    const int tid = threadIdx.x;
    const int T = tiecnt[row];
    const int less = lesscnt[row];
    const int need = CTX - less;

    __shared__ float kvs[D_MAIN];
    __shared__ int   sel[CTX];
    __shared__ float svals[CTX];
    __shared__ float sv[MAXTIE];
    __shared__ unsigned hist[256];
    __shared__ unsigned sh_bin, sh_need;
    __shared__ int c1, c2;
    __shared__ float red[128];

    if (tid < D_MAIN)
        kvs[tid] = join_f32(kh[(size_t)row * D_MAIN + tid], kl[(size_t)row * D_MAIN + tid]);
    if (tid < CTX && tid < less) sel[tid] = idx_out[row * CTX + tid];
    __syncthreads();

    if (T <= need) {
        for (int t = tid; t < T; t += 256) {
            sel[less + t] = tiebuf[(size_t)row * MAXTIE + t];
            idx_out[row * CTX + less + t] = sel[less + t];
        }
    } else {
        for (int t = tid; t < T; t += 256) {
            const int c = tiebuf[(size_t)row * MAXTIE + t];
            const u16* ch = ckh + (size_t)c * D_MAIN;
            const u16* cl = ckl + (size_t)c * D_MAIN;
            float s = 0.f;
            for (int d = 0; d < D_MAIN; d += 4) {
                const ushort4 h4 = *(const ushort4*)(ch + d);
                const ushort4 l4 = *(const ushort4*)(cl + d);
                s += kvs[d+0] * join_f32(h4.x, l4.x) + kvs[d+1] * join_f32(h4.y, l4.y)
                   + kvs[d+2] * join_f32(h4.z, l4.z) + kvs[d+3] * join_f32(h4.w, l4.w);
            }
            sv[t] = ck2[c] - 2.f * s;
        }
        __syncthreads();

        unsigned prefix = 0;
        int plen = 0;
        int nd = need;
        for (int pass = 0; pass < 4; ++pass) {
            const int shift = 24 - 8 * pass;
            hist[tid] = 0;
            __syncthreads();
            for (int t = tid; t < T; t += 256) {
                const unsigned u = f2u_mono(sv[t]);
                if (plen == 0 || (u >> (32 - plen)) == prefix)
                    atomicAdd(&hist[(u >> shift) & 255u], 1u);
            }
            __syncthreads();
            if (tid == 0) {
                int cum = 0;
                for (int bb = 0; bb < 256; ++bb) {
                    const int h = (int)hist[bb];
                    if (cum + h >= nd) { sh_bin = (unsigned)bb; sh_need = (unsigned)(nd - cum); break; }
                    cum += h;
                }
            }
            __syncthreads();
            prefix = (prefix << 8) | sh_bin;
            nd = (int)sh_need;
            plen += 8;
            __syncthreads();
        }
        const unsigned Tf = prefix;
        const int nl2 = need - nd;
        if (tid == 0) { c1 = 0; c2 = 0; }
        __syncthreads();
        for (int t = tid; t < T; t += 256) {
            const unsigned u = f2u_mono(sv[t]);
            if (u < Tf) {
                const int p = atomicAdd(&c1, 1);
                sel[less + p] = tiebuf[(size_t)row * MAXTIE + t];
                idx_out[row * CTX + less + p] = sel[less + p];
            } else if (u == Tf) {
                const int p = atomicAdd(&c2, 1);
                if (p < nd) {
                    sel[less + nl2 + p] = tiebuf[(size_t)row * MAXTIE + t];
                    idx_out[row * CTX + less + nl2 + p] = sel[less + nl2 + p];
                }
            }
        }
    }
    __syncthreads();

    const int wv = tid >> 6, lane = tid & 63;
    for (int c = wv; c < CTX; c += 4) {
        const int id = sel[c];
        const ushort4 h4 = *(const ushort4*)(ckh + (size_t)id * D_MAIN + lane * 4);
        const ushort4 l4 = *(const ushort4*)(ckl + (size_t)id * D_MAIN + lane * 4);
        float s = kvs[lane*4+0] * join_f32(h4.x, l4.x)
                + kvs[lane*4+1] * join_f32(h4.y, l4.y)
                + kvs[lane*4+2] * join_f32(h4.z, l4.z)
                + kvs[lane*4+3] * join_f32(h4.w, l4.w);
        #pragma unroll
        for (int off = 32; off; off >>= 1) s += __shfl_down(s, off, 64);
        if (lane == 0) svals[c] = ck2[id] - 2.f * s;
    }
    __syncthreads();

    if (tid < 128) {
        const float v = (tid < CTX) ? -svals[tid] : -1e30f;
        red[tid] = v;
        __builtin_amdgcn_s_barrier();
    }
    __syncthreads();
    if (tid < 128) {
        for (int s = 64; s > 0; s >>= 1) {
            if (tid < s) red[tid] = fmaxf(red[tid], red[tid + s]);
            __builtin_amdgcn_s_barrier();
        }
    }
    __syncthreads();
    const float mx = red[0];
    __syncthreads();
    float e = 0.f;
    if (tid < 128) {
        e = (tid < CTX) ? __expf(-svals[tid] - mx) : 0.f;
        red[tid] = e;
    }
    __syncthreads();
    if (tid < 128) {
        for (int s = 64; s > 0; s >>= 1) {
            if (tid < s) red[tid] += red[tid + s];
            __builtin_amdgcn_s_barrier();
        }
    }
    __syncthreads();
    if (tid < CTX) probs[row * CTX + tid] = e / red[0];
}

// ---------------------------------------------------------------------------
// u[b,j] = sum_c probs[b*CTX+c] * t2[(b0+b)*CTX... row bc][j]  (fp32, split out)
// One block per b (local); 256 threads x 2 cols.
// ---------------------------------------------------------------------------
__global__ __launch_bounds__(256)
void wsum_kernel(const u16* __restrict__ t2h, const float* __restrict__ probs,
                 int b_base, u16* __restrict__ uh, u16* __restrict__ ul)
{
    const int bl = blockIdx.x;              // chunk-local b
    const int b = b_base + bl;
    const int j0 = threadIdx.x * 2;
    __shared__ float pr[CTX];
    if (threadIdx.x < CTX) pr[threadIdx.x] = probs[b * CTX + threadIdx.x];
    __syncthreads();
    float a0 = 0.f, a1 = 0.f;
    const u16* base = t2h + (size_t)bl * CTX * D_BLOCK;
    for (int c = 0; c < CTX; ++c) {
        const float p = pr[c];
        a0 = fmaf(p, bits_to_f32(base[(size_t)c * D_BLOCK + j0]),     a0);
        a1 = fmaf(p, bits_to_f32(base[(size_t)c * D_BLOCK + j0 + 1]), a1);
    }
    u16 h, l;
    split_f32(a0, h, l);
    uh[(size_t)b * D_BLOCK + j0] = h;  ul[(size_t)b * D_BLOCK + j0] = l;
    split_f32(a1, h, l);
    uh[(size_t)b * D_BLOCK + j0 + 1] = h;  ul[(size_t)b * D_BLOCK + j0 + 1] = l;
}

// ---------------------------------------------------------------------------
// h_x[b,d] += sum_c probs[bc] * label_emb[cand_y[idx[bc]], d]
// ---------------------------------------------------------------------------
__global__ __launch_bounds__(256)
void mixlab_kernel(float* __restrict__ h, const float* __restrict__ probs,
                   const int* __restrict__ idx, const int* __restrict__ cy,
                   const float* __restrict__ label_emb)
{
    const int b = blockIdx.x;
    const int d = threadIdx.x;
    float acc = 0.f;
    for (int c = 0; c < CTX; ++c) {
        const int bc = b * CTX + c;
        acc = fmaf(probs[bc], label_emb[(size_t)cy[idx[bc]] * D_MAIN + d], acc);
    }
    h[(size_t)b * D_MAIN + d] += acc;
}

// ---------------------------------------------------------------------------
// host-side orchestration
// ---------------------------------------------------------------------------
static inline dim3 g128(int M, int N) {
    return dim3((unsigned)((N + 127) / 128), (unsigned)((M + 127) / 128));
}

struct EncW {
    const u16 *WlinTh, *WlinTl, *e0W1Th, *e0W1Tl, *e0W2Th, *e0W2Tl,
              *e1W1Th, *e1W1Tl, *e1W2Th, *e1W2Tl, *KWTh, *KWTl;
    const float *b_lin, *e0b1, *e0b2, *e1g, *e1b, *e1b1, *e1b2, *mixg, *mixb, *Kb;
};

// R10-proven encoder: fp32 H stream + split activations, split weights (3 MFMA)
static void encode_rows_split(const u16* Xh, const u16* Xl, int R, const EncW& w,
                              float* H, u16* Hh, u16* Hl, u16* Th, u16* Tl,
                              u16* TNh, u16* TNl, u16* Kh, u16* Kl,
                              hipStream_t stream)
{
    dim3 blk(256);
    gemm_split_nt<false,true,false,false, true,true,false, true,true,false><<<g128(R, D_MAIN), blk, 0, stream>>>(
        Xh, Xl, w.WlinTh, w.WlinTl, w.b_lin, nullptr, H, Hh, Hl, R, D_MAIN, D_IN);
    gemm_split_nt<true,true,false,false, false,true,false, true,true,false><<<g128(R, D_BLOCK), blk, 0, stream>>>(
        Hh, Hl, w.e0W1Th, w.e0W1Tl, w.e0b1, nullptr, nullptr, Th, Tl, R, D_BLOCK, D_MAIN);
    gemm_split_nt<false,true,true,false, true,false,false, true,true,false><<<g128(R, D_MAIN), blk, 0, stream>>>(
        Th, Tl, w.e0W2Th, w.e0W2Tl, w.e0b2, H, H, nullptr, nullptr, R, D_MAIN, D_BLOCK);
    ln_kernel<false,true><<<R, 256, 0, stream>>>(H, w.e1g, w.e1b, nullptr, TNh, TNl);
    gemm_split_nt<true,true,false,false, false,true,false, true,true,false><<<g128(R, D_BLOCK), blk, 0, stream>>>(
        TNh, TNl, w.e1W1Th, w.e1W1Tl, w.e1b1, nullptr, nullptr, Th, Tl, R, D_BLOCK, D_MAIN);
    gemm_split_nt<false,true,true,false, true,false,false, true,true,false><<<g128(R, D_MAIN), blk, 0, stream>>>(
        Th, Tl, w.e1W2Th, w.e1W2Tl, w.e1b2, H, H, nullptr, nullptr, R, D_MAIN, D_BLOCK);
    ln_kernel<false,true><<<R, 256, 0, stream>>>(H, w.mixg, w.mixb, nullptr, TNh, TNl);
    gemm_split_nt<false,true,false,false, false,true,false, true,true,false><<<g128(R, D_MAIN), blk, 0, stream>>>(
        TNh, TNl, w.KWTh, w.KWTl, w.Kb, nullptr, nullptr, Kh, Kl, R, D_MAIN, D_MAIN);
}

extern "C" void kernel_launch(void* const* d_in, const int* in_sizes, int n_in,
                              void* d_out, int out_size, void* d_ws, size_t ws_size,
                              hipStream_t stream)
{
    const float* x        = (const float*)d_in[0];
    const float* cand_x   = (const float*)d_in[1];
    const int*   cand_y   = (const int*)  d_in[2];
    const float* W_lin    = (const float*)d_in[4];
    const float* b_lin    = (const float*)d_in[5];
    const float* e0W1     = (const float*)d_in[6];
    const float* e0b1     = (const float*)d_in[7];
    const float* e0W2     = (const float*)d_in[8];
    const float* e0b2     = (const float*)d_in[9];
    const float* e1g      = (const float*)d_in[10];
    const float* e1b      = (const float*)d_in[11];
    const float* e1W1     = (const float*)d_in[12];
    const float* e1b1     = (const float*)d_in[13];
    const float* e1W2     = (const float*)d_in[14];
    const float* e1b2     = (const float*)d_in[15];
    const float* mixg     = (const float*)d_in[16];
    const float* mixb     = (const float*)d_in[17];
    const float* K_W      = (const float*)d_in[18];
    const float* K_b      = (const float*)d_in[19];
    const float* label_emb= (const float*)d_in[20];
    const float* T_W1     = (const float*)d_in[21];
    const float* T_b1     = (const float*)d_in[22];
    const float* T_W2     = (const float*)d_in[23];
    const float* p0g      = (const float*)d_in[24];
    const float* p0b      = (const float*)d_in[25];
    const float* p0W1     = (const float*)d_in[26];
    const float* p0b1     = (const float*)d_in[27];
    const float* p0W2     = (const float*)d_in[28];
    const float* p0b2     = (const float*)d_in[29];
    const float* p1g      = (const float*)d_in[30];
    const float* p1b      = (const float*)d_in[31];
    const float* p1W1     = (const float*)d_in[32];
    const float* p1b1     = (const float*)d_in[33];
    const float* p1W2     = (const float*)d_in[34];
    const float* p1b2     = (const float*)d_in[35];
    const float* headg    = (const float*)d_in[36];
    const float* headb    = (const float*)d_in[37];
    const float* head_W   = (const float*)d_in[38];
    const float* head_bias= (const float*)d_in[39];

    char* ws = (char*)d_ws;
    size_t off = 0;
    auto alloc = [&](size_t bytes) -> char* {
        char* p = ws + off;
        off += (bytes + 255) & ~(size_t)255;
        return p;
    };

    u16* in_h   = (u16*)alloc((size_t)NTOT * D_IN * 2);
    u16* in_l   = (u16*)alloc((size_t)NTOT * D_IN * 2);
    u16* allk_h = (u16*)alloc((size_t)NTOT * D_MAIN * 2);
    u16* allk_l = (u16*)alloc((size_t)NTOT * D_MAIN * 2);
    float* ck2  = (float*)alloc((size_t)N_CAND * 4);
    float* h_x  = (float*)alloc((size_t)B_ROWS * D_MAIN * 4);
    float* tn_x = (float*)alloc((size_t)B_ROWS * D_MAIN * 4);
    u16* tnb_h  = (u16*)alloc((size_t)B_ROWS * D_MAIN * 2);
    u16* tnb_l  = (u16*)alloc((size_t)B_ROWS * D_MAIN * 2);
    u16* tb_h   = (u16*)alloc((size_t)B_ROWS * D_BLOCK * 2);
    u16* tb_l   = (u16*)alloc((size_t)B_ROWS * D_BLOCK * 2);
    u16* u_h    = (u16*)alloc((size_t)B_ROWS * D_BLOCK * 2);
    u16* u_l    = (u16*)alloc((size_t)B_ROWS * D_BLOCK * 2);
    int*   idx  = (int*)  alloc((size_t)B_ROWS * CTX * 4);
    float* probs= (float*)alloc((size_t)B_ROWS * CTX * 4);
    int* tiebuf = (int*)  alloc((size_t)B_ROWS * MAXTIE * 4);
    int* tiecnt = (int*)  alloc((size_t)B_ROWS * 4);
    int* lesscnt= (int*)  alloc((size_t)B_ROWS * 4);

    auto allocW = [&](int R, int C, u16** h, u16** l) {
        *h = (u16*)alloc((size_t)R * C * 2);
        *l = (u16*)alloc((size_t)R * C * 2);
    };
    u16 *WlinTh, *WlinTl, *e0W1Th, *e0W1Tl, *e0W2Th, *e0W2Tl,
        *e1W1Th, *e1W1Tl, *e1W2Th, *e1W2Tl, *KWTh, *KWTl,
        *TW1Th, *TW1Tl, *TW2Th, *TW2Tl,
        *p0W1Th, *p0W1Tl, *p0W2Th, *p0W2Tl, *p1W1Th, *p1W1Tl, *p1W2Th, *p1W2Tl;
    allocW(D_IN,   D_MAIN, &WlinTh, &WlinTl);
    allocW(D_MAIN, D_BLOCK,&e0W1Th, &e0W1Tl);
    allocW(D_BLOCK,D_MAIN, &e0W2Th, &e0W2Tl);
    allocW(D_MAIN, D_BLOCK,&e1W1Th, &e1W1Tl);
    allocW(D_BLOCK,D_MAIN, &e1W2Th, &e1W2Tl);
    allocW(D_MAIN, D_MAIN, &KWTh,   &KWTl);
    allocW(D_MAIN, D_BLOCK,&TW1Th,  &TW1Tl);
    allocW(D_BLOCK,D_MAIN, &TW2Th,  &TW2Tl);
    allocW(D_MAIN, D_BLOCK,&p0W1Th, &p0W1Tl);
    allocW(D_BLOCK,D_MAIN, &p0W2Th, &p0W2Tl);
    allocW(D_MAIN, D_BLOCK,&p1W1Th, &p1W1Tl);
    allocW(D_BLOCK,D_MAIN, &p1W2Th, &p1W2Tl);

    u16* k_x_h = allk_h + (size_t)N_CAND * D_MAIN;
    u16* k_x_l = allk_l + (size_t)N_CAND * D_MAIN;
    u16* x_in_h = in_h + (size_t)N_CAND * D_IN;
    u16* x_in_l = in_l + (size_t)N_CAND * D_IN;

    const size_t pool_avail = (ws_size > off) ? (ws_size - off) : 0;
    int rc_enc = (int)(pool_avail / 5120);
    if (rc_enc > NTOT) rc_enc = NTOT;
    if (rc_enc < 6250) rc_enc = 6250;
    int mb_ch = (int)(pool_avail / ((size_t)2 * N_CAND));
    if (mb_ch > B_ROWS) mb_ch = B_ROWS;
    mb_ch &= ~127;
    if (mb_ch < 128)    mb_ch = 128;
    int bb_ch = (int)(pool_avail / ((size_t)CTX * D_BLOCK * 2));   // t2h only
    if (bb_ch > B_ROWS) bb_ch = B_ROWS;
    if (bb_ch < 64)     bb_ch = 64;

    char* pool = ws + off;
    dim3 blk(256);

    // 0) conversions
    {
        f32_to_split_kernel<<<(N_CAND*D_IN + 255)/256, blk, 0, stream>>>(cand_x, in_h, in_l, N_CAND*D_IN);
        f32_to_split_kernel<<<(B_ROWS*D_IN + 255)/256, blk, 0, stream>>>(x, x_in_h, x_in_l, B_ROWS*D_IN);
        TrD12 tr;
        tr.d[0]  = { W_lin, WlinTh, WlinTl, D_IN,   D_MAIN };
        tr.d[1]  = { e0W1,  e0W1Th, e0W1Tl, D_MAIN, D_BLOCK };
        tr.d[2]  = { e0W2,  e0W2Th, e0W2Tl, D_BLOCK,D_MAIN };
        tr.d[3]  = { e1W1,  e1W1Th, e1W1Tl, D_MAIN, D_BLOCK };
        tr.d[4]  = { e1W2,  e1W2Th, e1W2Tl, D_BLOCK,D_MAIN };
        tr.d[5]  = { K_W,   KWTh,   KWTl,   D_MAIN, D_MAIN };
        tr.d[6]  = { T_W1,  TW1Th,  TW1Tl,  D_MAIN, D_BLOCK };
        tr.d[7]  = { T_W2,  TW2Th,  TW2Tl,  D_BLOCK,D_MAIN };
        tr.d[8]  = { p0W1,  p0W1Th, p0W1Tl, D_MAIN, D_BLOCK };
        tr.d[9]  = { p0W2,  p0W2Th, p0W2Tl, D_BLOCK,D_MAIN };
        tr.d[10] = { p1W1,  p1W1Th, p1W1Tl, D_MAIN, D_BLOCK };
        tr.d[11] = { p1W2,  p1W2Th, p1W2Tl, D_BLOCK,D_MAIN };
        transpose_all_kernel<<<dim3(512, 12), blk, 0, stream>>>(tr);
    }

    EncW w = { WlinTh, WlinTl, e0W1Th, e0W1Tl, e0W2Th, e0W2Tl,
               e1W1Th, e1W1Tl, e1W2Th, e1W2Tl, KWTh, KWTl,
               b_lin, e0b1, e0b2, e1g, e1b, e1b1, e1b2, mixg, mixb, K_b };

    // 1) combined encode (candidates + x)
    for (int r0 = 0; r0 < NTOT; r0 += rc_enc) {
        const int R = (NTOT - r0 < rc_enc) ? (NTOT - r0) : rc_enc;
        char* p = pool;
        float* Hc = (float*)p;        p += (size_t)rc_enc * D_MAIN * 4;
        u16* Hh  = (u16*)p;           p += (size_t)rc_enc * D_MAIN * 2;
        u16* Hl  = (u16*)p;           p += (size_t)rc_enc * D_MAIN * 2;
        u16* Th  = (u16*)p;           p += (size_t)rc_enc * D_BLOCK * 2;
        u16* Tl  = (u16*)p;           p += (size_t)rc_enc * D_BLOCK * 2;
        u16* TNh = (u16*)p;           p += (size_t)rc_enc * D_MAIN * 2;
        u16* TNl = (u16*)p;
        encode_rows_split(in_h + (size_t)r0 * D_IN, in_l + (size_t)r0 * D_IN,
                          R, w, Hc, Hh, Hl, Th, Tl, TNh, TNl,
                          allk_h + (size_t)r0 * D_MAIN,
                          allk_l + (size_t)r0 * D_MAIN, stream);
        const int lo = (r0 > N_CAND) ? r0 : N_CAND;
        const int hi = (r0 + R < NTOT) ? r0 + R : NTOT;
        if (lo < hi) {
            const int n = (hi - lo) * D_MAIN;
            copy_rows_kernel<<<(n + 255)/256, blk, 0, stream>>>(
                Hc + (size_t)(lo - r0) * D_MAIN, h_x + (size_t)(lo - N_CAND) * D_MAIN, n);
        }
    }

    // 2) candidate norms
    cn2_kernel<<<N_CAND, 64, 0, stream>>>(allk_h, allk_l, ck2);

    // 3+4) distance keys (bf16-hi only) + top-96 select
    for (int m0 = 0; m0 < B_ROWS; m0 += mb_ch) {
        const int R = (B_ROWS - m0 < mb_ch) ? (B_ROWS - m0) : mb_ch;
        u16* s_keys = (u16*)pool;
        dim3 grid((unsigned)((R + 127) / 128), (unsigned)((N_CAND + 127) / 128));
        gemm_split_nt<false,false,false,true, false,false,false, false,false,true><<<grid, blk, 0, stream>>>(
            k_x_h + (size_t)m0 * D_MAIN, nullptr,
            allk_h, nullptr, ck2, nullptr, nullptr, s_keys, nullptr,
            R, N_CAND, D_MAIN);
        topk96_u16_kernel<<<R, 1024, 0, stream>>>(
            s_keys, idx + m0 * CTX, tiebuf + (size_t)m0 * MAXTIE,
            tiecnt + m0, lesscnt + m0);
    }

    // 5) fused exact tie-break + sval + softmax
    select_kernel<<<B_ROWS, 256, 0, stream>>>(k_x_h, k_x_l, allk_h, allk_l, ck2,
                                              tiebuf, tiecnt, lesscnt, idx, probs);

    // 6) T-MLP: GEMM1 (fused gather) -> t2h; u = probs . t2 (assoc. collapse)
    for (int b0 = 0; b0 < B_ROWS; b0 += bb_ch) {
        const int rows = (B_ROWS - b0 < bb_ch) ? (B_ROWS - b0) : bb_ch;
        const int R = rows * CTX;
        u16* th = (u16*)pool;
        gemm_tmlp1<<<g128(R, D_BLOCK), blk, 0, stream>>>(
            k_x_h, k_x_l, allk_h, allk_l, idx + b0 * CTX, b0,
            TW1Th, TW1Tl, T_b1, th, R, D_BLOCK, D_MAIN);
        wsum_kernel<<<rows, 256, 0, stream>>>(th, probs, b0, u_h, u_l);
    }
    // label mix, then h_x += u @ W2 (split x split, residual h_x)
    mixlab_kernel<<<B_ROWS, 256, 0, stream>>>(h_x, probs, idx, cand_y, label_emb);
    gemm_split_nt<false,false,true,false, true,false,false, true,true,false><<<g128(B_ROWS, D_MAIN), blk, 0, stream>>>(
        u_h, u_l, TW2Th, TW2Tl, nullptr, h_x, h_x, nullptr, nullptr,
        B_ROWS, D_MAIN, D_BLOCK);

    // 7) post blocks (split MFMA, fp32-quality)
    ln_kernel<false,true><<<B_ROWS, 256, 0, stream>>>(h_x, p0g, p0b, nullptr, tnb_h, tnb_l);
    gemm_split_nt<true,true,false,false, false,true,false, true,true,false><<<g128(B_ROWS, D_BLOCK), blk, 0, stream>>>(
        tnb_h, tnb_l, p0W1Th, p0W1Tl, p0b1, nullptr, nullptr, tb_h, tb_l, B_ROWS, D_BLOCK, D_MAIN);
    gemm_split_nt<false,true,true,false, true,false,false, true,true,false><<<g128(B_ROWS, D_MAIN), blk, 0, stream>>>(
        tb_h, tb_l, p0W2Th, p0W2Tl, p0b2, h_x, h_x, nullptr, nullptr, B_ROWS, D_MAIN, D_BLOCK);
    ln_kernel<false,true><<<B_ROWS, 256, 0, stream>>>(h_x, p1g, p1b, nullptr, tnb_h, tnb_l);
    gemm_split_nt<true,true,false,false, false,true,false, true,true,false><<<g128(B_ROWS, D_BLOCK), blk, 0, stream>>>(
        tnb_h, tnb_l, p1W1Th, p1W1Tl, p1b1, nullptr, nullptr, tb_h, tb_l, B_ROWS, D_BLOCK, D_MAIN);
    gemm_split_nt<false,true,true,false, true,false,false, true,true,false><<<g128(B_ROWS, D_MAIN), blk, 0, stream>>>(
        tb_h, tb_l, p1W2Th, p1W2Tl, p1b2, h_x, h_x, nullptr, nullptr, B_ROWS, D_MAIN, D_BLOCK);

    // 8) head (fp32)
    ln_kernel<true,false><<<B_ROWS, 256, 0, stream>>>(h_x, headg, headb, tn_x, nullptr, nullptr);
    gemm_head<<<dim3(1, (B_ROWS + 63) / 64), blk, 0, stream>>>(
        tn_x, head_W, head_bias, (float*)d_out, B_ROWS, N_OUT, D_MAIN);
}